// Round 9
// baseline (522.232 us; speedup 1.0000x reference)
//
#include <hip/hip_runtime.h>

#define D     256
#define K     8192
#define NROWS 32768      // B*T
#define BETA  0.025f
#define TAU_NEW 4e-4f    // bf16-split path margin (fine-err ~3e-5, ref quant ~6e-5)
#define TAU_OLD 2e-4f    // fp32 fallback path margin

typedef __bf16 bf16x8 __attribute__((ext_vector_type(8)));
typedef unsigned short ushort8v __attribute__((ext_vector_type(8)));
typedef float f32x16 __attribute__((ext_vector_type(16)));

#define MFMA(a,b,c) __builtin_amdgcn_mfma_f32_32x32x16_bf16(a,b,c,0,0,0)

typedef __attribute__((address_space(3))) unsigned int lds_uint;
typedef __attribute__((address_space(1))) unsigned int glb_uint;
__device__ __forceinline__ void gld16(const void* g, void* l) {
    // async global->LDS, 16B/lane; LDS dest = wave-uniform base + lane*16
    __builtin_amdgcn_global_load_lds((const glb_uint*)g, (lds_uint*)l, 16, 0, 0);
}

__device__ __forceinline__ unsigned short bf_rn(float x) {
    unsigned u = __float_as_uint(x);
    return (unsigned short)((u + 0x7FFFu + ((u >> 16) & 1u)) >> 16);
}
__device__ __forceinline__ void split2(float x, unsigned short& h, unsigned short& l) {
    h = bf_rn(x);
    float hf = __uint_as_float(((unsigned)h) << 16);
    l = bf_rn(x - hf);
}

// ---------------------------------------------------------------------------
// numpy-exact row sum-of-squares (pairwise_sum emulation, n=256); full rows
// (round-5 verified version)
// ---------------------------------------------------------------------------
__global__ __launch_bounds__(256)
void np_sumsq_kernel(const float* __restrict__ src, float* __restrict__ dst,
                     int nrows) {
    const int tid  = threadIdx.x;
    const int w    = tid >> 6;
    const int lane = tid & 63;
    const int row  = blockIdx.x * 4 + w;
    if (row >= nrows) return;
    const float* a = src + (size_t)row * D;
    float r = 0.0f;
    if (lane < 16) {
        const float* h = a + (lane >> 3) * 128;
        const int j = lane & 7;
        float v = h[j];
        r = __fmul_rn(v, v);
        #pragma unroll
        for (int i = 8; i < 128; i += 8) {
            float u = h[i + j];
            r = __fadd_rn(r, __fmul_rn(u, u));
        }
    }
    float rr[16];
    #pragma unroll
    for (int t = 0; t < 16; ++t) rr[t] = __shfl(r, t, 64);
    if (lane == 0) {
        float h0 = __fadd_rn(__fadd_rn(__fadd_rn(rr[0], rr[1]), __fadd_rn(rr[2], rr[3])),
                             __fadd_rn(__fadd_rn(rr[4], rr[5]), __fadd_rn(rr[6], rr[7])));
        float h1 = __fadd_rn(__fadd_rn(__fadd_rn(rr[8], rr[9]), __fadd_rn(rr[10], rr[11])),
                             __fadd_rn(__fadd_rn(rr[12], rr[13]), __fadd_rn(rr[14], rr[15])));
        dst[row] = __fadd_rn(h0, h1);
    }
}

// Same, but only for flagged rows (x2 is needed only in the exact fixup).
__global__ __launch_bounds__(64)
void np_sumsq_flagged_kernel(const float* __restrict__ ze,
                             const int* __restrict__ nflag,
                             const int* __restrict__ flags,
                             float* __restrict__ x2, int cap) {
    const int lane = threadIdx.x;
    const int nf   = min(nflag[0], cap);
    for (int f = blockIdx.x; f < nf; f += gridDim.x) {
        const int row = flags[f];
        const float* a = ze + (size_t)row * D;
        float r = 0.0f;
        if (lane < 16) {
            const float* h = a + (lane >> 3) * 128;
            const int j = lane & 7;
            float v = h[j];
            r = __fmul_rn(v, v);
            #pragma unroll
            for (int i = 8; i < 128; i += 8) {
                float u = h[i + j];
                r = __fadd_rn(r, __fmul_rn(u, u));
            }
        }
        float rr[16];
        #pragma unroll
        for (int t = 0; t < 16; ++t) rr[t] = __shfl(r, t, 64);
        if (lane == 0) {
            float h0 = __fadd_rn(__fadd_rn(__fadd_rn(rr[0], rr[1]), __fadd_rn(rr[2], rr[3])),
                                 __fadd_rn(__fadd_rn(rr[4], rr[5]), __fadd_rn(rr[6], rr[7])));
            float h1 = __fadd_rn(__fadd_rn(__fadd_rn(rr[8], rr[9]), __fadd_rn(rr[10], rr[11])),
                                 __fadd_rn(__fadd_rn(rr[12], rr[13]), __fadd_rn(rr[14], rr[15])));
            x2[row] = __fadd_rn(h0, h1);
        }
    }
}

// ---------------------------------------------------------------------------
// Pack codebook into MFMA A-fragment order, bf16 hi/lo (round-5 verified).
// [tile t(256)][chunk c(16)][split s(2)][lane l(64)][j(8)] ushort.
// ---------------------------------------------------------------------------
__global__ __launch_bounds__(256)
void pack_cb_kernel(const float* __restrict__ cb, unsigned short* __restrict__ cbp) {
    const int t  = blockIdx.x;
    const int l  = threadIdx.x & 63;
    const int cq = threadIdx.x >> 6;
    const int row = t * 32 + (l & 31);
    const int db  = 8 * (l >> 5);
    #pragma unroll
    for (int ci = 0; ci < 4; ++ci) {
        const int c  = cq * 4 + ci;
        const int d0 = c * 16 + db;
        float4 v0 = *reinterpret_cast<const float4*>(&cb[(size_t)row * D + d0]);
        float4 v1 = *reinterpret_cast<const float4*>(&cb[(size_t)row * D + d0 + 4]);
        float xv[8] = {v0.x, v0.y, v0.z, v0.w, v1.x, v1.y, v1.z, v1.w};
        ushort8v uh, ul;
        #pragma unroll
        for (int j = 0; j < 8; ++j) {
            unsigned short hh, ll;
            split2(xv[j], hh, ll);
            uh[j] = hh; ul[j] = ll;
        }
        *reinterpret_cast<ushort8v*>(cbp + (size_t)t * 16384 + (c * 2 + 0) * 512 + l * 8) = uh;
        *reinterpret_cast<ushort8v*>(cbp + (size_t)t * 16384 + (c * 2 + 1) * 512 + l * 8) = ul;
    }
}

// ---------------------------------------------------------------------------
// MFMA distance GEMM + per-row top-2 (round-5 body, verbatim).
// Deltas vs the round-5-verified kernel (bisect, exactly two):
//  1) amdgpu_waves_per_eu(2,2): LDS (64KB/block) caps at 2 blocks/CU anyway;
//     giving the allocator the 256-VGPR budget removes the ~28MB/dispatch
//     scratch spill round-5 counters showed.
//  2) sched_barrier(0) pins the async stage ISSUE before the compute/barrier
//     so the compiler cannot sink it past __syncthreads (cross-wave LDS race).
// ---------------------------------------------------------------------------
__global__ __attribute__((amdgpu_waves_per_eu(2, 2))) __launch_bounds__(256)
void mfma_argmin_kernel(const float* __restrict__ ze,
                        const unsigned short* __restrict__ cbp,
                        const float* __restrict__ c2,
                        float2* __restrict__ tops, int* __restrict__ topi) {
    __shared__ unsigned short lds[2 * 16384];   // 2 x 32 KB tile buffers
    const int tid = threadIdx.x;
    const int l   = tid & 63;
    const int w   = tid >> 6;
    const int ks  = blockIdx.x & 1;
    const int nb  = blockIdx.x >> 1;
    const int n   = nb * 128 + w * 32 + (l & 31);
    const int h   = l >> 5;

    // ---- z rows -> B fragments (hi/lo), kept in registers (128 VGPR)
    bf16x8 Bh[16], Bl[16];
    {
        const float* zr = ze + (size_t)n * D + 8 * h;
        #pragma unroll
        for (int c = 0; c < 16; ++c) {
            float4 v0 = *reinterpret_cast<const float4*>(zr + c * 16);
            float4 v1 = *reinterpret_cast<const float4*>(zr + c * 16 + 4);
            float xv[8] = {v0.x, v0.y, v0.z, v0.w, v1.x, v1.y, v1.z, v1.w};
            ushort8v uh, ul;
            #pragma unroll
            for (int j = 0; j < 8; ++j) {
                unsigned short hh, ll;
                split2(xv[j], hh, ll);
                uh[j] = hh; ul[j] = ll;
            }
            Bh[c] = __builtin_bit_cast(bf16x8, uh);
            Bl[c] = __builtin_bit_cast(bf16x8, ul);
        }
    }

    const int t0 = ks * 128;
    const uint4* gsrc = reinterpret_cast<const uint4*>(cbp);  // 16B units; tile = 2048

    // async stage: wave w stages its quarter (512 uint4) via 8 calls
    auto stage = [&](int t, int buf) {
        const uint4* g = gsrc + (size_t)t * 2048 + w * 512 + l;
        uint4* lb = reinterpret_cast<uint4*>(lds + buf * 16384) + w * 512;
        #pragma unroll
        for (int r = 0; r < 8; ++r)
            gld16(g + r * 64, lb + r * 64);
    };

    stage(t0, 0);
    __builtin_amdgcn_sched_barrier(0);   // pin stage issue before the barrier
    __syncthreads();   // drains vmcnt: tile 0 resident

    float b1 = 3.4e38f, b2 = 3.4e38f;
    int   i1 = 0;
    int   cur = 0;

    for (int ti = 0; ti < 128; ++ti) {
        const int t = t0 + ti;
        if (ti + 1 < 128) stage(t + 1, cur ^ 1);    // async into other buffer
        __builtin_amdgcn_sched_barrier(0);           // stage must issue HERE

        const uint4* abuf = reinterpret_cast<const uint4*>(lds + cur * 16384);
        f32x16 accA, accB;
        #pragma unroll
        for (int i = 0; i < 16; ++i) { accA[i] = 0.0f; accB[i] = 0.0f; }
        #pragma unroll
        for (int c = 0; c < 16; ++c) {
            bf16x8 Ah = __builtin_bit_cast(bf16x8, abuf[(c * 2 + 0) * 64 + l]);
            bf16x8 Al = __builtin_bit_cast(bf16x8, abuf[(c * 2 + 1) * 64 + l]);
            accA = MFMA(Ah, Bh[c], accA);
            accB = MFMA(Ah, Bl[c], accB);
            accB = MFMA(Al, Bh[c], accB);
        }
        // epilogue: scores + running top-2 (codes ascend in processing order)
        const float* c2t = c2 + t * 32 + 4 * h;
        const int base = t * 32 + 4 * h;
        #pragma unroll
        for (int g = 0; g < 4; ++g) {
            float4 cv = *reinterpret_cast<const float4*>(c2t + 8 * g);
            #pragma unroll
            for (int q = 0; q < 4; ++q) {
                const int reg = g * 4 + q;
                float dot = accA[reg] + accB[reg];
                float cc  = (q == 0) ? cv.x : (q == 1) ? cv.y : (q == 2) ? cv.z : cv.w;
                float s   = fmaf(-2.0f, dot, cc);
                int code  = base + 8 * g + q;
                bool lt = s < b1;
                b2 = fminf(b2, lt ? b1 : s);
                i1 = lt ? code : i1;
                b1 = lt ? s : b1;
            }
        }
        __syncthreads();   // drains vmcnt (next tile staged) + frees buf[cur]
        cur ^= 1;
    }

    // merge lane l <-> l^32 (same row n)
    float ob1 = __shfl_xor(b1, 32);
    float ob2 = __shfl_xor(b2, 32);
    int   oi1 = __shfl_xor(i1, 32);
    bool take = (ob1 < b1) || (ob1 == b1 && oi1 < i1);
    float nb2 = fminf(fmaxf(b1, ob1), fminf(b2, ob2));
    float nb1 = take ? ob1 : b1;
    int   ni1 = take ? oi1 : i1;
    if (l < 32) {
        tops[(size_t)n * 2 + ks] = make_float2(nb1, nb2);
        topi[(size_t)n * 2 + ks] = ni1;
    }
}

// ---------------------------------------------------------------------------
// Merge the two k-split top-2 entries per row; flag near-ties (round-5).
// ---------------------------------------------------------------------------
__global__ __launch_bounds__(256)
void ksplit_merge_kernel(const float2* __restrict__ tops, const int* __restrict__ topi,
                         int* __restrict__ idx_out, float* __restrict__ idxf_out,
                         int* __restrict__ nflag, int* __restrict__ flags, float tau) {
    const int n = blockIdx.x * 256 + threadIdx.x;
    float2 e0 = tops[(size_t)n * 2 + 0];
    float2 e1 = tops[(size_t)n * 2 + 1];
    int    i0 = topi[(size_t)n * 2 + 0];
    int    i1v = topi[(size_t)n * 2 + 1];
    bool take = (e1.x < e0.x) || (e1.x == e0.x && i1v < i0);
    float b1 = take ? e1.x : e0.x;
    int   bi = take ? i1v : i0;
    float b2 = fminf(fmaxf(e0.x, e1.x), fminf(e0.y, e1.y));
    idx_out[n]  = bi;
    idxf_out[n] = (float)bi;
    if (b2 - b1 < tau) {
        int p = atomicAdd(nflag, 1);
        flags[p] = n;
    }
}

// ---------------------------------------------------------------------------
// Inverted-loop exact fixup (round-5 verified). fix1: block owns 16 codes
// (512 blocks), loops flagged rows; numpy-fp32-emulated metric:
// tmp4 = fl32(fl32(x2 - 2*fl32(dot_f64)) + c2).  fix2: per-row 512-way merge.
// ---------------------------------------------------------------------------
__global__ __launch_bounds__(256)
void fix1_kernel(const float* __restrict__ ze, const float* __restrict__ cb,
                 const float* __restrict__ c2, const float* __restrict__ x2,
                 const int* __restrict__ nflag, const int* __restrict__ flags,
                 float* __restrict__ scr_s, int* __restrict__ scr_i, int cap) {
    __shared__ float sz[D];
    __shared__ float sbest[16];
    __shared__ int   sbi[16];
    const int tid  = threadIdx.x;
    const int cl   = tid >> 4;
    const int dt   = tid & 15;
    const int code = blockIdx.x * 16 + cl;
    const int nf   = min(nflag[0], cap);
    for (int f = 0; f < nf; ++f) {
        const int row = flags[f];
        __syncthreads();
        sz[tid] = ze[(size_t)row * D + tid];
        __syncthreads();
        double dot = 0.0;
        const float* cr = cb + (size_t)code * D + dt * 16;
        #pragma unroll
        for (int i = 0; i < 16; ++i)
            dot = fma((double)sz[dt * 16 + i], (double)cr[i], dot);
        #pragma unroll
        for (int o = 1; o < 16; o <<= 1)
            dot += __shfl_xor(dot, o);
        if (dt == 0) {
            float P  = (float)dot;
            float t3 = __fadd_rn(x2[row], __fmul_rn(-2.0f, P));
            float t4 = __fadd_rn(t3, c2[code]);
            sbest[cl] = t4; sbi[cl] = code;
        }
        __syncthreads();
        if (tid == 0) {
            float bs = sbest[0]; int bi = sbi[0];
            #pragma unroll
            for (int c = 1; c < 16; ++c)
                if (sbest[c] < bs) { bs = sbest[c]; bi = sbi[c]; }
            scr_s[(size_t)f * 512 + blockIdx.x] = bs;
            scr_i[(size_t)f * 512 + blockIdx.x] = bi;
        }
    }
}

__global__ __launch_bounds__(256)
void fix2_kernel(const int* __restrict__ nflag, const int* __restrict__ flags,
                 const float* __restrict__ scr_s, const int* __restrict__ scr_i,
                 int* __restrict__ idx_out, float* __restrict__ idxf_out, int cap) {
    __shared__ float ss[256];
    __shared__ int   si[256];
    const int tid = threadIdx.x;
    const int nf  = min(nflag[0], cap);
    for (int f = blockIdx.x; f < nf; f += gridDim.x) {
        float s0 = scr_s[(size_t)f * 512 + tid];
        int   j0 = scr_i[(size_t)f * 512 + tid];
        float s1 = scr_s[(size_t)f * 512 + 256 + tid];
        int   j1 = scr_i[(size_t)f * 512 + 256 + tid];
        bool take = (s1 < s0) || (s1 == s0 && j1 < j0);
        ss[tid] = take ? s1 : s0;
        si[tid] = take ? j1 : j0;
        __syncthreads();
        for (int o = 128; o; o >>= 1) {
            if (tid < o) {
                if (ss[tid + o] < ss[tid] ||
                    (ss[tid + o] == ss[tid] && si[tid + o] < si[tid])) {
                    ss[tid] = ss[tid + o]; si[tid] = si[tid + o];
                }
            }
            __syncthreads();
        }
        if (tid == 0) {
            const int row = flags[f];
            idx_out[row]  = si[0];
            idxf_out[row] = (float)si[0];
        }
        __syncthreads();
    }
}

// ---------------------------------------------------------------------------
// FALLBACK (round-3 verified): fp32 vector GEMM + top-2, fp64 fixup.
// ---------------------------------------------------------------------------
__global__ __launch_bounds__(512)
void argmin_fp32_kernel(const float* __restrict__ ze, const float* __restrict__ cb,
                        const float* __restrict__ c2,
                        int* __restrict__ idx_out, float* __restrict__ idxf_out,
                        int* __restrict__ nflag, int* __restrict__ flags) {
    __shared__ float smem[12672];
    float* a_s = smem;
    float* b_s = smem + 32 * 128;
    const int tid  = threadIdx.x;
    const int tx   = tid & 31;
    const int ty   = tid >> 5;
    const int row0 = blockIdx.x * 128;
    float b1[8], b2[8];
    int   i1[8];
    #pragma unroll
    for (int r = 0; r < 8; ++r) { b1[r] = 3.4e38f; b2[r] = 3.4e38f; i1[r] = 0; }
    for (int kt = 0; kt < K; kt += 256) {
        float acc[8][8];
        #pragma unroll
        for (int r = 0; r < 8; ++r)
            #pragma unroll
            for (int c = 0; c < 8; ++c) acc[r][c] = 0.0f;
        for (int dc = 0; dc < D; dc += 32) {
            __syncthreads();
            #pragma unroll
            for (int j = 0; j < 2; ++j) {
                int p = tid + j * 512, ar = p >> 3, ad = (p & 7) << 2;
                float4 v = *reinterpret_cast<const float4*>(&ze[(size_t)(row0 + ar) * D + dc + ad]);
                a_s[(ad + 0) * 128 + ar] = v.x; a_s[(ad + 1) * 128 + ar] = v.y;
                a_s[(ad + 2) * 128 + ar] = v.z; a_s[(ad + 3) * 128 + ar] = v.w;
            }
            #pragma unroll
            for (int j = 0; j < 4; ++j) {
                int p = tid + j * 512, br = p >> 3, bd = (p & 7) << 2;
                float4 v = *reinterpret_cast<const float4*>(&cb[(size_t)(kt + br) * D + dc + bd]);
                b_s[(bd + 0) * 256 + br] = v.x; b_s[(bd + 1) * 256 + br] = v.y;
                b_s[(bd + 2) * 256 + br] = v.z; b_s[(bd + 3) * 256 + br] = v.w;
            }
            __syncthreads();
            #pragma unroll 4
            for (int d = 0; d < 32; ++d) {
                float4 a0  = *reinterpret_cast<const float4*>(&a_s[d * 128 + ty * 4]);
                float4 a1  = *reinterpret_cast<const float4*>(&a_s[d * 128 + 64 + ty * 4]);
                float4 b0  = *reinterpret_cast<const float4*>(&b_s[d * 256 + tx * 4]);
                float4 b1v = *reinterpret_cast<const float4*>(&b_s[d * 256 + 128 + tx * 4]);
                float av[8] = {a0.x, a0.y, a0.z, a0.w, a1.x, a1.y, a1.z, a1.w};
                float bv[8] = {b0.x, b0.y, b0.z, b0.w, b1v.x, b1v.y, b1v.z, b1v.w};
                #pragma unroll
                for (int r = 0; r < 8; ++r)
                    #pragma unroll
                    for (int c = 0; c < 8; ++c)
                        acc[r][c] = fmaf(av[r], bv[c], acc[r][c]);
            }
        }
        float4 cs0 = *reinterpret_cast<const float4*>(&c2[kt + tx * 4]);
        float4 cs1 = *reinterpret_cast<const float4*>(&c2[kt + 128 + tx * 4]);
        float cv[8] = {cs0.x, cs0.y, cs0.z, cs0.w, cs1.x, cs1.y, cs1.z, cs1.w};
        #pragma unroll
        for (int r = 0; r < 8; ++r)
            #pragma unroll
            for (int c = 0; c < 8; ++c) {
                int col = kt + ((c < 4) ? (tx * 4 + c) : (128 + tx * 4 + (c - 4)));
                float s = fmaf(-2.0f, acc[r][c], cv[c]);
                if (s < b1[r]) { b2[r] = b1[r]; b1[r] = s; i1[r] = col; }
                else if (s < b2[r]) { b2[r] = s; }
            }
    }
    __syncthreads();
    float* rs1 = smem;
    int*   ri  = (int*)(smem + 4224);
    float* rs2 = smem + 8448;
    #pragma unroll
    for (int r = 0; r < 8; ++r) {
        int lrow = (r >> 2) * 64 + ty * 4 + (r & 3);
        rs1[lrow * 33 + tx] = b1[r]; ri[lrow * 33 + tx] = i1[r]; rs2[lrow * 33 + tx] = b2[r];
    }
    __syncthreads();
    if (tid < 128) {
        float B1 = 3.4e38f, B2 = 3.4e38f;
        int I1 = 0;
        #pragma unroll 4
        for (int t = 0; t < 32; ++t) {
            float s1 = rs1[tid * 33 + t]; int j1 = ri[tid * 33 + t]; float s2 = rs2[tid * 33 + t];
            if (s1 < B1 || (s1 == B1 && j1 < I1)) { B2 = fminf(B2, B1); B1 = s1; I1 = j1; }
            else B2 = fminf(B2, s1);
            B2 = fminf(B2, s2);
        }
        int grow = row0 + tid;
        idx_out[grow] = I1;
        idxf_out[grow] = (float)I1;
        if (B2 - B1 < TAU_OLD) { int p = atomicAdd(nflag, 1); flags[p] = grow; }
    }
}

__global__ __launch_bounds__(256)
void fix_old_kernel(const float* __restrict__ ze, const float* __restrict__ cb,
                    const float* __restrict__ c2, const float* __restrict__ x2,
                    const int* __restrict__ nflag, const int* __restrict__ flags,
                    int* __restrict__ idx_out, float* __restrict__ idxf_out) {
    __shared__ __align__(16) float sx[D];
    __shared__ float sbest[256];
    __shared__ int   sidx[256];
    const int tid = threadIdx.x;
    const int n   = nflag[0];
    for (int f = blockIdx.x; f < n; f += gridDim.x) {
        __syncthreads();
        const int row = flags[f];
        sx[tid] = ze[(size_t)row * D + tid];
        const float x2r = x2[row];
        __syncthreads();
        const float4* sx4 = reinterpret_cast<const float4*>(sx);
        float best = 3.4e38f; int bi = K;
        for (int k = tid; k < K; k += 256) {
            const float4* cbr = reinterpret_cast<const float4*>(&cb[(size_t)k * D]);
            double dot = 0.0;
            #pragma unroll 8
            for (int d4 = 0; d4 < D / 4; ++d4) {
                float4 c = cbr[d4]; float4 x = sx4[d4];
                dot = fma((double)x.x, (double)c.x, dot);
                dot = fma((double)x.y, (double)c.y, dot);
                dot = fma((double)x.z, (double)c.z, dot);
                dot = fma((double)x.w, (double)c.w, dot);
            }
            float P  = (float)dot;
            float t3 = __fadd_rn(x2r, __fmul_rn(-2.0f, P));
            float t4 = __fadd_rn(t3, c2[k]);
            if (t4 < best || (t4 == best && k < bi)) { best = t4; bi = k; }
        }
        sbest[tid] = best; sidx[tid] = bi;
        __syncthreads();
        for (int o = 128; o; o >>= 1) {
            if (tid < o) {
                if (sbest[tid + o] < sbest[tid] ||
                    (sbest[tid + o] == sbest[tid] && sidx[tid + o] < sidx[tid])) {
                    sbest[tid] = sbest[tid + o]; sidx[tid] = sidx[tid + o];
                }
            }
            __syncthreads();
        }
        if (tid == 0) { idx_out[row] = sidx[0]; idxf_out[row] = (float)sidx[0]; }
    }
}

// ---------------------------------------------------------------------------
// gather z_q = cb[idx] + loss reduction (deterministic two-stage)
// ---------------------------------------------------------------------------
__global__ __launch_bounds__(256)
void gather_loss_kernel(const float* __restrict__ ze, const float* __restrict__ cb,
                        const int* __restrict__ idx, float* __restrict__ zq,
                        float* __restrict__ partial) {
    const int tid  = threadIdx.x;
    const int w    = tid >> 6;
    const int lane = tid & 63;
    const int n    = blockIdx.x * 4 + w;
    const int k    = idx[n];
    float4 q = *reinterpret_cast<const float4*>(&cb[(size_t)k * D + lane * 4]);
    float4 z = *reinterpret_cast<const float4*>(&ze[(size_t)n * D + lane * 4]);
    *reinterpret_cast<float4*>(&zq[(size_t)n * D + lane * 4]) = q;
    float dx = z.x - q.x, dy = z.y - q.y, dz = z.z - q.z, dw = z.w - q.w;
    float s = dx * dx + dy * dy + dz * dz + dw * dw;
    #pragma unroll
    for (int o = 32; o; o >>= 1) s += __shfl_down(s, o);
    __shared__ float ws4[4];
    if (lane == 0) ws4[w] = s;
    __syncthreads();
    if (tid == 0) partial[blockIdx.x] = ws4[0] + ws4[1] + ws4[2] + ws4[3];
}

__global__ __launch_bounds__(256)
void final_loss_kernel(const float* __restrict__ partial, float* __restrict__ out) {
    __shared__ float sm[256];
    const int tid = threadIdx.x;
    float s = 0.0f;
    for (int i = tid; i < 8192; i += 256) s += partial[i];
    sm[tid] = s;
    __syncthreads();
    #pragma unroll
    for (int o = 128; o; o >>= 1) {
        if (tid < o) sm[tid] += sm[tid + o];
        __syncthreads();
    }
    if (tid == 0)
        out[0] = sm[0] * (1.0f + BETA) / (float)(NROWS * D);
}

// ---------------------------------------------------------------------------
extern "C" void kernel_launch(void* const* d_in, const int* in_sizes, int n_in,
                              void* d_out, int out_size, void* d_ws, size_t ws_size,
                              hipStream_t stream) {
    const float* ze = (const float*)d_in[0];
    const float* cb = (const float*)d_in[1];

    float* out  = (float*)d_out;
    float* zq   = out;
    float* idxf = out + (size_t)NROWS * D;
    float* loss = out + (size_t)NROWS * D + NROWS;

    char* ws = (char*)d_ws;
    float*  c2      = (float*) (ws);
    float*  x2      = (float*) (ws + 32768);
    int*    idx     = (int*)   (ws + 163840);
    float*  partial = (float*) (ws + 294912);
    int*    nflag   = (int*)   (ws + 327680);
    int*    flags   = (int*)   (ws + 327696);
    float2* tops    = (float2*)(ws + 458768);
    int*    topi    = (int*)   (ws + 983056);
    unsigned short* cbp = (unsigned short*)(ws + 1245200);   // 8.4 MB
    float*  scr_s   = (float*) (ws + 9633808);
    const size_t scr_base = 9633808;

    const size_t need_min = scr_base + (size_t)2048 * 4096;
    const bool newpath = ws_size >= need_min;
    int cap = 0;
    int* scr_i = nullptr;
    if (newpath) {
        size_t avail = (ws_size - scr_base) / 4096;
        cap = (int)(avail > 8192 ? 8192 : avail);
        scr_i = (int*)(ws + scr_base + (size_t)cap * 2048);
    }

    hipMemsetAsync(nflag, 0, sizeof(int), stream);
    hipLaunchKernelGGL(np_sumsq_kernel, dim3(K / 4), dim3(256), 0, stream, cb, c2, K);

    if (newpath) {
        hipLaunchKernelGGL(pack_cb_kernel,     dim3(256), dim3(256), 0, stream, cb, cbp);
        hipLaunchKernelGGL(mfma_argmin_kernel, dim3(512), dim3(256), 0, stream,
                           ze, cbp, c2, tops, topi);
        hipLaunchKernelGGL(ksplit_merge_kernel, dim3(NROWS / 256), dim3(256), 0, stream,
                           tops, topi, idx, idxf, nflag, flags, TAU_NEW);
        hipLaunchKernelGGL(np_sumsq_flagged_kernel, dim3(128), dim3(64), 0, stream,
                           ze, nflag, flags, x2, cap);
        hipLaunchKernelGGL(fix1_kernel, dim3(512), dim3(256), 0, stream,
                           ze, cb, c2, x2, nflag, flags, scr_s, scr_i, cap);
        hipLaunchKernelGGL(fix2_kernel, dim3(64), dim3(256), 0, stream,
                           nflag, flags, scr_s, scr_i, idx, idxf, cap);
    } else {
        hipLaunchKernelGGL(argmin_fp32_kernel, dim3(NROWS / 128), dim3(512), 0, stream,
                           ze, cb, c2, idx, idxf, nflag, flags);
        hipLaunchKernelGGL(np_sumsq_flagged_kernel, dim3(128), dim3(64), 0, stream,
                           ze, nflag, flags, x2, NROWS);
        hipLaunchKernelGGL(fix_old_kernel, dim3(256), dim3(256), 0, stream,
                           ze, cb, c2, x2, nflag, flags, idx, idxf);
    }

    hipLaunchKernelGGL(gather_loss_kernel, dim3(NROWS / 4), dim3(256), 0, stream,
                       ze, cb, idx, zq, partial);
    hipLaunchKernelGGL(final_loss_kernel, dim3(1), dim3(256), 0, stream,
                       partial, loss);
}

// Round 10
// 518.842 us; speedup vs baseline: 1.0065x; 1.0065x over previous
//
#include <hip/hip_runtime.h>

#define D     256
#define K     8192
#define NROWS 32768      // B*T
#define BETA  0.025f
#define TAU_NEW 4e-4f    // bf16-split path margin (fine-err ~3e-5, ref quant ~6e-5)
#define TAU_OLD 2e-4f    // fp32 fallback path margin

typedef __bf16 bf16x8 __attribute__((ext_vector_type(8)));
typedef unsigned short ushort8v __attribute__((ext_vector_type(8)));
typedef float f32x4 __attribute__((ext_vector_type(4)));

#define MFMA16(a,b,c) __builtin_amdgcn_mfma_f32_16x16x32_bf16(a,b,c,0,0,0)

typedef __attribute__((address_space(3))) unsigned int lds_uint;
typedef __attribute__((address_space(1))) unsigned int glb_uint;
__device__ __forceinline__ void gld16(const void* g, void* l) {
    // async global->LDS, 16B/lane; LDS dest = wave-uniform base + lane*16
    __builtin_amdgcn_global_load_lds((const glb_uint*)g, (lds_uint*)l, 16, 0, 0);
}

__device__ __forceinline__ unsigned short bf_rn(float x) {
    unsigned u = __float_as_uint(x);
    return (unsigned short)((u + 0x7FFFu + ((u >> 16) & 1u)) >> 16);
}
__device__ __forceinline__ void split2(float x, unsigned short& h, unsigned short& l) {
    h = bf_rn(x);
    float hf = __uint_as_float(((unsigned)h) << 16);
    l = bf_rn(x - hf);
}

// ---------------------------------------------------------------------------
// numpy-exact row sum-of-squares (pairwise_sum emulation, n=256); full rows
// ---------------------------------------------------------------------------
__global__ __launch_bounds__(256)
void np_sumsq_kernel(const float* __restrict__ src, float* __restrict__ dst,
                     int nrows) {
    const int tid  = threadIdx.x;
    const int w    = tid >> 6;
    const int lane = tid & 63;
    const int row  = blockIdx.x * 4 + w;
    if (row >= nrows) return;
    const float* a = src + (size_t)row * D;
    float r = 0.0f;
    if (lane < 16) {
        const float* h = a + (lane >> 3) * 128;
        const int j = lane & 7;
        float v = h[j];
        r = __fmul_rn(v, v);
        #pragma unroll
        for (int i = 8; i < 128; i += 8) {
            float u = h[i + j];
            r = __fadd_rn(r, __fmul_rn(u, u));
        }
    }
    float rr[16];
    #pragma unroll
    for (int t = 0; t < 16; ++t) rr[t] = __shfl(r, t, 64);
    if (lane == 0) {
        float h0 = __fadd_rn(__fadd_rn(__fadd_rn(rr[0], rr[1]), __fadd_rn(rr[2], rr[3])),
                             __fadd_rn(__fadd_rn(rr[4], rr[5]), __fadd_rn(rr[6], rr[7])));
        float h1 = __fadd_rn(__fadd_rn(__fadd_rn(rr[8], rr[9]), __fadd_rn(rr[10], rr[11])),
                             __fadd_rn(__fadd_rn(rr[12], rr[13]), __fadd_rn(rr[14], rr[15])));
        dst[row] = __fadd_rn(h0, h1);
    }
}

// Same, but only for flagged rows (x2 is needed only in the exact fixup).
__global__ __launch_bounds__(64)
void np_sumsq_flagged_kernel(const float* __restrict__ ze,
                             const int* __restrict__ nflag,
                             const int* __restrict__ flags,
                             float* __restrict__ x2, int cap) {
    const int lane = threadIdx.x;
    const int nf   = min(nflag[0], cap);
    for (int f = blockIdx.x; f < nf; f += gridDim.x) {
        const int row = flags[f];
        const float* a = ze + (size_t)row * D;
        float r = 0.0f;
        if (lane < 16) {
            const float* h = a + (lane >> 3) * 128;
            const int j = lane & 7;
            float v = h[j];
            r = __fmul_rn(v, v);
            #pragma unroll
            for (int i = 8; i < 128; i += 8) {
                float u = h[i + j];
                r = __fadd_rn(r, __fmul_rn(u, u));
            }
        }
        float rr[16];
        #pragma unroll
        for (int t = 0; t < 16; ++t) rr[t] = __shfl(r, t, 64);
        if (lane == 0) {
            float h0 = __fadd_rn(__fadd_rn(__fadd_rn(rr[0], rr[1]), __fadd_rn(rr[2], rr[3])),
                                 __fadd_rn(__fadd_rn(rr[4], rr[5]), __fadd_rn(rr[6], rr[7])));
            float h1 = __fadd_rn(__fadd_rn(__fadd_rn(rr[8], rr[9]), __fadd_rn(rr[10], rr[11])),
                                 __fadd_rn(__fadd_rn(rr[12], rr[13]), __fadd_rn(rr[14], rr[15])));
            x2[row] = __fadd_rn(h0, h1);
        }
    }
}

// ---------------------------------------------------------------------------
// Pack codebook into 16x16x32 MFMA A-fragment order, bf16 hi/lo.
// ushort offset = ((((t*8 + c)*2 + cs)*2 + sp)*64 + l)*8 + j
// value = split_sp( cb[t*32 + cs*16 + (l&15)][c*32 + 8*(l>>4) + j] )
// (A row = l&15; k-slot map k = 8*(l>>4)+j used identically for A and B, so
//  any hardware k-permutation cancels; only the M/N lane maps must be right.)
// ---------------------------------------------------------------------------
__global__ __launch_bounds__(256)
void pack_cb_kernel(const float* __restrict__ cb, unsigned short* __restrict__ cbp) {
    const int t = blockIdx.x;           // 256 tiles of 32 codes
    const int l = threadIdx.x & 63;
    const int q = threadIdx.x >> 6;     // 0..3 -> chunks {2q, 2q+1}
    const int h = l >> 4;
    #pragma unroll
    for (int ci = 0; ci < 2; ++ci) {
        const int c = q * 2 + ci;
        #pragma unroll
        for (int cs = 0; cs < 2; ++cs) {
            const int code = t * 32 + cs * 16 + (l & 15);
            const int d0   = c * 32 + 8 * h;
            float4 v0 = *reinterpret_cast<const float4*>(&cb[(size_t)code * D + d0]);
            float4 v1 = *reinterpret_cast<const float4*>(&cb[(size_t)code * D + d0 + 4]);
            float xv[8] = {v0.x, v0.y, v0.z, v0.w, v1.x, v1.y, v1.z, v1.w};
            ushort8v uh, ul;
            #pragma unroll
            for (int j = 0; j < 8; ++j) {
                unsigned short hh, ll;
                split2(xv[j], hh, ll);
                uh[j] = hh; ul[j] = ll;
            }
            const size_t base = (((size_t)t * 8 + c) * 2 + cs) * 2;
            *reinterpret_cast<ushort8v*>(cbp + (base + 0) * 512 + l * 8) = uh;
            *reinterpret_cast<ushort8v*>(cbp + (base + 1) * 512 + l * 8) = ul;
        }
    }
}

// ---------------------------------------------------------------------------
// MFMA distance GEMM + per-row top-2, 16x16x32 geometry.
// 8 waves x 16 rows = 128 rows/block; K split 2 ways (blockIdx&1).
// B fragments: 8 chunks x (hi,lo) = 64 VGPRs (was 128 with 32x32x16) -> total
// register demand ~115 < 128 cap -> no spill (round-9 counters showed the
// allocator pins 128 VGPRs regardless of waves_per_eu hints; shrink demand
// instead of raising the budget).
// score = c2[k] - 2*(hh + hl + lh); arithmetic identical to round 9.
// ---------------------------------------------------------------------------
__global__ __launch_bounds__(512)
void mfma_argmin_kernel(const float* __restrict__ ze,
                        const unsigned short* __restrict__ cbp,
                        const float* __restrict__ c2,
                        float2* __restrict__ tops, int* __restrict__ topi) {
    __shared__ unsigned short lds[2 * 16384];   // 2 x 32 KB tile buffers
    const int tid = threadIdx.x;
    const int l   = tid & 63;
    const int w   = tid >> 6;          // 0..7
    const int ks  = blockIdx.x & 1;
    const int nb  = blockIdx.x >> 1;   // 0..255
    const int n   = nb * 128 + w * 16 + (l & 15);
    const int h   = l >> 4;            // 0..3

    // ---- z row -> B fragments (hi/lo), 8 chunks, register-resident (64 VGPR)
    bf16x8 Bh[8], Bl[8];
    {
        const float* zr = ze + (size_t)n * D + 8 * h;
        #pragma unroll
        for (int c = 0; c < 8; ++c) {
            float4 v0 = *reinterpret_cast<const float4*>(zr + c * 32);
            float4 v1 = *reinterpret_cast<const float4*>(zr + c * 32 + 4);
            float xv[8] = {v0.x, v0.y, v0.z, v0.w, v1.x, v1.y, v1.z, v1.w};
            ushort8v uh, ul;
            #pragma unroll
            for (int j = 0; j < 8; ++j) {
                unsigned short hh, ll;
                split2(xv[j], hh, ll);
                uh[j] = hh; ul[j] = ll;
            }
            Bh[c] = __builtin_bit_cast(bf16x8, uh);
            Bl[c] = __builtin_bit_cast(bf16x8, ul);
        }
    }

    const int t0 = ks * 128;
    const uint4* gsrc = reinterpret_cast<const uint4*>(cbp);  // tile = 2048 uint4

    // async stage: 8 waves x 4 calls x 64 lanes = 2048 uint4
    auto stage = [&](int t, int buf) {
        const uint4* gbase = gsrc + (size_t)t * 2048;
        uint4* lbase = reinterpret_cast<uint4*>(lds + buf * 16384);
        #pragma unroll
        for (int r = 0; r < 4; ++r) {
            const int idx = r * 512 + w * 64;   // wave-uniform
            gld16(gbase + idx + l, lbase + idx);
        }
    };

    stage(t0, 0);
    __builtin_amdgcn_sched_barrier(0);   // pin stage issue before the barrier
    __syncthreads();   // drains vmcnt: tile 0 resident

    float b1 = 3.4e38f, b2 = 3.4e38f;
    int   i1 = 0;
    int   cur = 0;

    for (int ti = 0; ti < 128; ++ti) {
        const int t = t0 + ti;
        if (ti + 1 < 128) stage(t + 1, cur ^ 1);    // async into other buffer
        __builtin_amdgcn_sched_barrier(0);           // stage must issue HERE

        const uint4* abuf = reinterpret_cast<const uint4*>(lds + cur * 16384);
        f32x4 accA[2], accB[2];   // per code-subtile: hh chain, (hl+lh) chain
        #pragma unroll
        for (int cs = 0; cs < 2; ++cs)
            #pragma unroll
            for (int i = 0; i < 4; ++i) { accA[cs][i] = 0.0f; accB[cs][i] = 0.0f; }

        #pragma unroll
        for (int c = 0; c < 8; ++c) {
            #pragma unroll
            for (int cs = 0; cs < 2; ++cs) {
                bf16x8 Ah = __builtin_bit_cast(bf16x8, abuf[((c * 2 + cs) * 2 + 0) * 64 + l]);
                bf16x8 Al = __builtin_bit_cast(bf16x8, abuf[((c * 2 + cs) * 2 + 1) * 64 + l]);
                accA[cs] = MFMA16(Ah, Bh[c], accA[cs]);
                accB[cs] = MFMA16(Ah, Bl[c], accB[cs]);
                accB[cs] = MFMA16(Al, Bh[c], accB[cs]);
            }
        }

        // scores: D mapping (m89): col=l&15 (z-row), row=(l>>4)*4+reg (code)
        float s[8];
        #pragma unroll
        for (int cs = 0; cs < 2; ++cs) {
            const int base = t * 32 + cs * 16 + h * 4;
            float4 cv = *reinterpret_cast<const float4*>(c2 + base);
            #pragma unroll
            for (int r = 0; r < 4; ++r) {
                float dot = accA[cs][r] + accB[cs][r];
                float cc  = (r == 0) ? cv.x : (r == 1) ? cv.y : (r == 2) ? cv.z : cv.w;
                s[cs * 4 + r] = fmaf(-2.0f, dot, cc);
            }
        }
        // top-2 of 8; codes ascend with index, 'a' side lower -> strict '<'
        float m1[4], m2[4]; int ix[4];
        #pragma unroll
        for (int p = 0; p < 4; ++p) {
            const int codeA = t * 32 + (p >> 1) * 16 + h * 4 + (p & 1) * 2;
            float sa = s[2 * p], sb = s[2 * p + 1];
            bool bl = sb < sa;
            m1[p] = bl ? sb : sa;
            m2[p] = bl ? sa : sb;
            ix[p] = codeA + (bl ? 1 : 0);
        }
        #pragma unroll
        for (int step = 1; step < 4; step <<= 1) {
            #pragma unroll
            for (int i = 0; i < 4; i += 2 * step) {
                const int a = i, b = i + step;
                float t2 = fminf(m2[a], m2[b]);
                bool bl = m1[b] < m1[a];
                float lose = bl ? m1[a] : m1[b];
                m2[a] = fminf(t2, lose);
                m1[a] = bl ? m1[b] : m1[a];
                ix[a] = bl ? ix[b] : ix[a];
            }
        }
        {
            bool lt = m1[0] < b1;   // earlier tiles = lower codes win ties
            b2 = fminf(fminf(b2, m2[0]), lt ? b1 : m1[0]);
            i1 = lt ? ix[0] : i1;
            b1 = lt ? m1[0] : b1;
        }

        __syncthreads();   // drains vmcnt (next tile staged) + frees buf[cur]
        cur ^= 1;
    }

    // merge across lanes sharing the same z-row: l ^ 16, then l ^ 32
    #pragma unroll
    for (int mask = 16; mask <= 32; mask <<= 1) {
        float os1 = __shfl_xor(b1, mask);
        float os2 = __shfl_xor(b2, mask);
        int   oi  = __shfl_xor(i1, mask);
        bool take = (os1 < b1) || (os1 == b1 && oi < i1);
        b2 = fminf(fmaxf(b1, os1), fminf(b2, os2));
        b1 = take ? os1 : b1;
        i1 = take ? oi  : i1;
    }
    if (l < 16) {
        tops[(size_t)n * 2 + ks] = make_float2(b1, b2);
        topi[(size_t)n * 2 + ks] = i1;
    }
}

// ---------------------------------------------------------------------------
// Merge the two k-split top-2 entries per row; flag near-ties (round-5).
// ---------------------------------------------------------------------------
__global__ __launch_bounds__(256)
void ksplit_merge_kernel(const float2* __restrict__ tops, const int* __restrict__ topi,
                         int* __restrict__ idx_out, float* __restrict__ idxf_out,
                         int* __restrict__ nflag, int* __restrict__ flags, float tau) {
    const int n = blockIdx.x * 256 + threadIdx.x;
    float2 e0 = tops[(size_t)n * 2 + 0];
    float2 e1 = tops[(size_t)n * 2 + 1];
    int    i0 = topi[(size_t)n * 2 + 0];
    int    i1v = topi[(size_t)n * 2 + 1];
    bool take = (e1.x < e0.x) || (e1.x == e0.x && i1v < i0);
    float b1 = take ? e1.x : e0.x;
    int   bi = take ? i1v : i0;
    float b2 = fminf(fmaxf(e0.x, e1.x), fminf(e0.y, e1.y));
    idx_out[n]  = bi;
    idxf_out[n] = (float)bi;
    if (b2 - b1 < tau) {
        int p = atomicAdd(nflag, 1);
        flags[p] = n;
    }
}

// ---------------------------------------------------------------------------
// Inverted-loop exact fixup (round-5 verified). fix1: block owns 16 codes
// (512 blocks), loops flagged rows; numpy-fp32-emulated metric:
// tmp4 = fl32(fl32(x2 - 2*fl32(dot_f64)) + c2).  fix2: per-row 512-way merge.
// ---------------------------------------------------------------------------
__global__ __launch_bounds__(256)
void fix1_kernel(const float* __restrict__ ze, const float* __restrict__ cb,
                 const float* __restrict__ c2, const float* __restrict__ x2,
                 const int* __restrict__ nflag, const int* __restrict__ flags,
                 float* __restrict__ scr_s, int* __restrict__ scr_i, int cap) {
    __shared__ float sz[D];
    __shared__ float sbest[16];
    __shared__ int   sbi[16];
    const int tid  = threadIdx.x;
    const int cl   = tid >> 4;
    const int dt   = tid & 15;
    const int code = blockIdx.x * 16 + cl;
    const int nf   = min(nflag[0], cap);
    for (int f = 0; f < nf; ++f) {
        const int row = flags[f];
        __syncthreads();
        sz[tid] = ze[(size_t)row * D + tid];
        __syncthreads();
        double dot = 0.0;
        const float* cr = cb + (size_t)code * D + dt * 16;
        #pragma unroll
        for (int i = 0; i < 16; ++i)
            dot = fma((double)sz[dt * 16 + i], (double)cr[i], dot);
        #pragma unroll
        for (int o = 1; o < 16; o <<= 1)
            dot += __shfl_xor(dot, o);
        if (dt == 0) {
            float P  = (float)dot;
            float t3 = __fadd_rn(x2[row], __fmul_rn(-2.0f, P));
            float t4 = __fadd_rn(t3, c2[code]);
            sbest[cl] = t4; sbi[cl] = code;
        }
        __syncthreads();
        if (tid == 0) {
            float bs = sbest[0]; int bi = sbi[0];
            #pragma unroll
            for (int c = 1; c < 16; ++c)
                if (sbest[c] < bs) { bs = sbest[c]; bi = sbi[c]; }
            scr_s[(size_t)f * 512 + blockIdx.x] = bs;
            scr_i[(size_t)f * 512 + blockIdx.x] = bi;
        }
    }
}

__global__ __launch_bounds__(256)
void fix2_kernel(const int* __restrict__ nflag, const int* __restrict__ flags,
                 const float* __restrict__ scr_s, const int* __restrict__ scr_i,
                 int* __restrict__ idx_out, float* __restrict__ idxf_out, int cap) {
    __shared__ float ss[256];
    __shared__ int   si[256];
    const int tid = threadIdx.x;
    const int nf  = min(nflag[0], cap);
    for (int f = blockIdx.x; f < nf; f += gridDim.x) {
        float s0 = scr_s[(size_t)f * 512 + tid];
        int   j0 = scr_i[(size_t)f * 512 + tid];
        float s1 = scr_s[(size_t)f * 512 + 256 + tid];
        int   j1 = scr_i[(size_t)f * 512 + 256 + tid];
        bool take = (s1 < s0) || (s1 == s0 && j1 < j0);
        ss[tid] = take ? s1 : s0;
        si[tid] = take ? j1 : j0;
        __syncthreads();
        for (int o = 128; o; o >>= 1) {
            if (tid < o) {
                if (ss[tid + o] < ss[tid] ||
                    (ss[tid + o] == ss[tid] && si[tid + o] < si[tid])) {
                    ss[tid] = ss[tid + o]; si[tid] = si[tid + o];
                }
            }
            __syncthreads();
        }
        if (tid == 0) {
            const int row = flags[f];
            idx_out[row]  = si[0];
            idxf_out[row] = (float)si[0];
        }
        __syncthreads();
    }
}

// ---------------------------------------------------------------------------
// FALLBACK (round-3 verified): fp32 vector GEMM + top-2, fp64 fixup.
// ---------------------------------------------------------------------------
__global__ __launch_bounds__(512)
void argmin_fp32_kernel(const float* __restrict__ ze, const float* __restrict__ cb,
                        const float* __restrict__ c2,
                        int* __restrict__ idx_out, float* __restrict__ idxf_out,
                        int* __restrict__ nflag, int* __restrict__ flags) {
    __shared__ float smem[12672];
    float* a_s = smem;
    float* b_s = smem + 32 * 128;
    const int tid  = threadIdx.x;
    const int tx   = tid & 31;
    const int ty   = tid >> 5;
    const int row0 = blockIdx.x * 128;
    float b1[8], b2[8];
    int   i1[8];
    #pragma unroll
    for (int r = 0; r < 8; ++r) { b1[r] = 3.4e38f; b2[r] = 3.4e38f; i1[r] = 0; }
    for (int kt = 0; kt < K; kt += 256) {
        float acc[8][8];
        #pragma unroll
        for (int r = 0; r < 8; ++r)
            #pragma unroll
            for (int c = 0; c < 8; ++c) acc[r][c] = 0.0f;
        for (int dc = 0; dc < D; dc += 32) {
            __syncthreads();
            #pragma unroll
            for (int j = 0; j < 2; ++j) {
                int p = tid + j * 512, ar = p >> 3, ad = (p & 7) << 2;
                float4 v = *reinterpret_cast<const float4*>(&ze[(size_t)(row0 + ar) * D + dc + ad]);
                a_s[(ad + 0) * 128 + ar] = v.x; a_s[(ad + 1) * 128 + ar] = v.y;
                a_s[(ad + 2) * 128 + ar] = v.z; a_s[(ad + 3) * 128 + ar] = v.w;
            }
            #pragma unroll
            for (int j = 0; j < 4; ++j) {
                int p = tid + j * 512, br = p >> 3, bd = (p & 7) << 2;
                float4 v = *reinterpret_cast<const float4*>(&cb[(size_t)(kt + br) * D + dc + bd]);
                b_s[(bd + 0) * 256 + br] = v.x; b_s[(bd + 1) * 256 + br] = v.y;
                b_s[(bd + 2) * 256 + br] = v.z; b_s[(bd + 3) * 256 + br] = v.w;
            }
            __syncthreads();
            #pragma unroll 4
            for (int d = 0; d < 32; ++d) {
                float4 a0  = *reinterpret_cast<const float4*>(&a_s[d * 128 + ty * 4]);
                float4 a1  = *reinterpret_cast<const float4*>(&a_s[d * 128 + 64 + ty * 4]);
                float4 b0  = *reinterpret_cast<const float4*>(&b_s[d * 256 + tx * 4]);
                float4 b1v = *reinterpret_cast<const float4*>(&b_s[d * 256 + 128 + tx * 4]);
                float av[8] = {a0.x, a0.y, a0.z, a0.w, a1.x, a1.y, a1.z, a1.w};
                float bv[8] = {b0.x, b0.y, b0.z, b0.w, b1v.x, b1v.y, b1v.z, b1v.w};
                #pragma unroll
                for (int r = 0; r < 8; ++r)
                    #pragma unroll
                    for (int c = 0; c < 8; ++c)
                        acc[r][c] = fmaf(av[r], bv[c], acc[r][c]);
            }
        }
        float4 cs0 = *reinterpret_cast<const float4*>(&c2[kt + tx * 4]);
        float4 cs1 = *reinterpret_cast<const float4*>(&c2[kt + 128 + tx * 4]);
        float cv[8] = {cs0.x, cs0.y, cs0.z, cs0.w, cs1.x, cs1.y, cs1.z, cs1.w};
        #pragma unroll
        for (int r = 0; r < 8; ++r)
            #pragma unroll
            for (int c = 0; c < 8; ++c) {
                int col = kt + ((c < 4) ? (tx * 4 + c) : (128 + tx * 4 + (c - 4)));
                float s = fmaf(-2.0f, acc[r][c], cv[c]);
                if (s < b1[r]) { b2[r] = b1[r]; b1[r] = s; i1[r] = col; }
                else if (s < b2[r]) { b2[r] = s; }
            }
    }
    __syncthreads();
    float* rs1 = smem;
    int*   ri  = (int*)(smem + 4224);
    float* rs2 = smem + 8448;
    #pragma unroll
    for (int r = 0; r < 8; ++r) {
        int lrow = (r >> 2) * 64 + ty * 4 + (r & 3);
        rs1[lrow * 33 + tx] = b1[r]; ri[lrow * 33 + tx] = i1[r]; rs2[lrow * 33 + tx] = b2[r];
    }
    __syncthreads();
    if (tid < 128) {
        float B1 = 3.4e38f, B2 = 3.4e38f;
        int I1 = 0;
        #pragma unroll 4
        for (int t = 0; t < 32; ++t) {
            float s1 = rs1[tid * 33 + t]; int j1 = ri[tid * 33 + t]; float s2 = rs2[tid * 33 + t];
            if (s1 < B1 || (s1 == B1 && j1 < I1)) { B2 = fminf(B2, B1); B1 = s1; I1 = j1; }
            else B2 = fminf(B2, s1);
            B2 = fminf(B2, s2);
        }
        int grow = row0 + tid;
        idx_out[grow] = I1;
        idxf_out[grow] = (float)I1;
        if (B2 - B1 < TAU_OLD) { int p = atomicAdd(nflag, 1); flags[p] = grow; }
    }
}

__global__ __launch_bounds__(256)
void fix_old_kernel(const float* __restrict__ ze, const float* __restrict__ cb,
                    const float* __restrict__ c2, const float* __restrict__ x2,
                    const int* __restrict__ nflag, const int* __restrict__ flags,
                    int* __restrict__ idx_out, float* __restrict__ idxf_out) {
    __shared__ __align__(16) float sx[D];
    __shared__ float sbest[256];
    __shared__ int   sidx[256];
    const int tid = threadIdx.x;
    const int n   = nflag[0];
    for (int f = blockIdx.x; f < n; f += gridDim.x) {
        __syncthreads();
        const int row = flags[f];
        sx[tid] = ze[(size_t)row * D + tid];
        const float x2r = x2[row];
        __syncthreads();
        const float4* sx4 = reinterpret_cast<const float4*>(sx);
        float best = 3.4e38f; int bi = K;
        for (int k = tid; k < K; k += 256) {
            const float4* cbr = reinterpret_cast<const float4*>(&cb[(size_t)k * D]);
            double dot = 0.0;
            #pragma unroll 8
            for (int d4 = 0; d4 < D / 4; ++d4) {
                float4 c = cbr[d4]; float4 x = sx4[d4];
                dot = fma((double)x.x, (double)c.x, dot);
                dot = fma((double)x.y, (double)c.y, dot);
                dot = fma((double)x.z, (double)c.z, dot);
                dot = fma((double)x.w, (double)c.w, dot);
            }
            float P  = (float)dot;
            float t3 = __fadd_rn(x2r, __fmul_rn(-2.0f, P));
            float t4 = __fadd_rn(t3, c2[k]);
            if (t4 < best || (t4 == best && k < bi)) { best = t4; bi = k; }
        }
        sbest[tid] = best; sidx[tid] = bi;
        __syncthreads();
        for (int o = 128; o; o >>= 1) {
            if (tid < o) {
                if (sbest[tid + o] < sbest[tid] ||
                    (sbest[tid + o] == sbest[tid] && sidx[tid + o] < sidx[tid])) {
                    sbest[tid] = sbest[tid + o]; sidx[tid] = sidx[tid + o];
                }
            }
            __syncthreads();
        }
        if (tid == 0) { idx_out[row] = sidx[0]; idxf_out[row] = (float)sidx[0]; }
    }
}

// ---------------------------------------------------------------------------
// gather z_q = cb[idx] + loss reduction (deterministic two-stage)
// ---------------------------------------------------------------------------
__global__ __launch_bounds__(256)
void gather_loss_kernel(const float* __restrict__ ze, const float* __restrict__ cb,
                        const int* __restrict__ idx, float* __restrict__ zq,
                        float* __restrict__ partial) {
    const int tid  = threadIdx.x;
    const int w    = tid >> 6;
    const int lane = tid & 63;
    const int n    = blockIdx.x * 4 + w;
    const int k    = idx[n];
    float4 q = *reinterpret_cast<const float4*>(&cb[(size_t)k * D + lane * 4]);
    float4 z = *reinterpret_cast<const float4*>(&ze[(size_t)n * D + lane * 4]);
    *reinterpret_cast<float4*>(&zq[(size_t)n * D + lane * 4]) = q;
    float dx = z.x - q.x, dy = z.y - q.y, dz = z.z - q.z, dw = z.w - q.w;
    float s = dx * dx + dy * dy + dz * dz + dw * dw;
    #pragma unroll
    for (int o = 32; o; o >>= 1) s += __shfl_down(s, o);
    __shared__ float ws4[4];
    if (lane == 0) ws4[w] = s;
    __syncthreads();
    if (tid == 0) partial[blockIdx.x] = ws4[0] + ws4[1] + ws4[2] + ws4[3];
}

__global__ __launch_bounds__(256)
void final_loss_kernel(const float* __restrict__ partial, float* __restrict__ out) {
    __shared__ float sm[256];
    const int tid = threadIdx.x;
    float s = 0.0f;
    for (int i = tid; i < 8192; i += 256) s += partial[i];
    sm[tid] = s;
    __syncthreads();
    #pragma unroll
    for (int o = 128; o; o >>= 1) {
        if (tid < o) sm[tid] += sm[tid + o];
        __syncthreads();
    }
    if (tid == 0)
        out[0] = sm[0] * (1.0f + BETA) / (float)(NROWS * D);
}

// ---------------------------------------------------------------------------
extern "C" void kernel_launch(void* const* d_in, const int* in_sizes, int n_in,
                              void* d_out, int out_size, void* d_ws, size_t ws_size,
                              hipStream_t stream) {
    const float* ze = (const float*)d_in[0];
    const float* cb = (const float*)d_in[1];

    float* out  = (float*)d_out;
    float* zq   = out;
    float* idxf = out + (size_t)NROWS * D;
    float* loss = out + (size_t)NROWS * D + NROWS;

    char* ws = (char*)d_ws;
    float*  c2      = (float*) (ws);
    float*  x2      = (float*) (ws + 32768);
    int*    idx     = (int*)   (ws + 163840);
    float*  partial = (float*) (ws + 294912);
    int*    nflag   = (int*)   (ws + 327680);
    int*    flags   = (int*)   (ws + 327696);
    float2* tops    = (float2*)(ws + 458768);
    int*    topi    = (int*)   (ws + 983056);
    unsigned short* cbp = (unsigned short*)(ws + 1245200);   // 8.4 MB
    float*  scr_s   = (float*) (ws + 9633808);
    const size_t scr_base = 9633808;

    const size_t need_min = scr_base + (size_t)2048 * 4096;
    const bool newpath = ws_size >= need_min;
    int cap = 0;
    int* scr_i = nullptr;
    if (newpath) {
        size_t avail = (ws_size - scr_base) / 4096;
        cap = (int)(avail > 8192 ? 8192 : avail);
        scr_i = (int*)(ws + scr_base + (size_t)cap * 2048);
    }

    hipMemsetAsync(nflag, 0, sizeof(int), stream);
    hipLaunchKernelGGL(np_sumsq_kernel, dim3(K / 4), dim3(256), 0, stream, cb, c2, K);

    if (newpath) {
        hipLaunchKernelGGL(pack_cb_kernel,     dim3(256), dim3(256), 0, stream, cb, cbp);
        hipLaunchKernelGGL(mfma_argmin_kernel, dim3(512), dim3(512), 0, stream,
                           ze, cbp, c2, tops, topi);
        hipLaunchKernelGGL(ksplit_merge_kernel, dim3(NROWS / 256), dim3(256), 0, stream,
                           tops, topi, idx, idxf, nflag, flags, TAU_NEW);
        hipLaunchKernelGGL(np_sumsq_flagged_kernel, dim3(128), dim3(64), 0, stream,
                           ze, nflag, flags, x2, cap);
        hipLaunchKernelGGL(fix1_kernel, dim3(512), dim3(256), 0, stream,
                           ze, cb, c2, x2, nflag, flags, scr_s, scr_i, cap);
        hipLaunchKernelGGL(fix2_kernel, dim3(64), dim3(256), 0, stream,
                           nflag, flags, scr_s, scr_i, idx, idxf, cap);
    } else {
        hipLaunchKernelGGL(argmin_fp32_kernel, dim3(NROWS / 128), dim3(512), 0, stream,
                           ze, cb, c2, idx, idxf, nflag, flags);
        hipLaunchKernelGGL(np_sumsq_flagged_kernel, dim3(128), dim3(64), 0, stream,
                           ze, nflag, flags, x2, NROWS);
        hipLaunchKernelGGL(fix_old_kernel, dim3(256), dim3(256), 0, stream,
                           ze, cb, c2, x2, nflag, flags, idx, idxf);
    }

    hipLaunchKernelGGL(gather_loss_kernel, dim3(NROWS / 4), dim3(256), 0, stream,
                       ze, cb, idx, zq, partial);
    hipLaunchKernelGGL(final_loss_kernel, dim3(1), dim3(256), 0, stream,
                       partial, loss);
}

// Round 11
// 507.267 us; speedup vs baseline: 1.0295x; 1.0228x over previous
//
#include <hip/hip_runtime.h>

#define D     256
#define K     8192
#define NROWS 32768      // B*T
#define BETA  0.025f
#define TAU_NEW 2e-3f    // fp16 single-product margin (score err sigma ~1.4e-4)
#define TAU_OLD 2e-4f    // fp32 fallback path margin

typedef _Float16 f16x8 __attribute__((ext_vector_type(8)));
typedef unsigned short ushort8v __attribute__((ext_vector_type(8)));
typedef float f32x16 __attribute__((ext_vector_type(16)));

#define MFMAH(a,b,c) __builtin_amdgcn_mfma_f32_32x32x16_f16(a,b,c,0,0,0)

typedef __attribute__((address_space(3))) unsigned int lds_uint;
typedef __attribute__((address_space(1))) unsigned int glb_uint;
__device__ __forceinline__ void gld16(const void* g, void* l) {
    // async global->LDS, 16B/lane; LDS dest = wave-uniform base + lane*16
    __builtin_amdgcn_global_load_lds((const glb_uint*)g, (lds_uint*)l, 16, 0, 0);
}

// ---------------------------------------------------------------------------
// numpy-exact row sum-of-squares (pairwise_sum emulation, n=256); full rows
// ---------------------------------------------------------------------------
__global__ __launch_bounds__(256)
void np_sumsq_kernel(const float* __restrict__ src, float* __restrict__ dst,
                     int nrows) {
    const int tid  = threadIdx.x;
    const int w    = tid >> 6;
    const int lane = tid & 63;
    const int row  = blockIdx.x * 4 + w;
    if (row >= nrows) return;
    const float* a = src + (size_t)row * D;
    float r = 0.0f;
    if (lane < 16) {
        const float* h = a + (lane >> 3) * 128;
        const int j = lane & 7;
        float v = h[j];
        r = __fmul_rn(v, v);
        #pragma unroll
        for (int i = 8; i < 128; i += 8) {
            float u = h[i + j];
            r = __fadd_rn(r, __fmul_rn(u, u));
        }
    }
    float rr[16];
    #pragma unroll
    for (int t = 0; t < 16; ++t) rr[t] = __shfl(r, t, 64);
    if (lane == 0) {
        float h0 = __fadd_rn(__fadd_rn(__fadd_rn(rr[0], rr[1]), __fadd_rn(rr[2], rr[3])),
                             __fadd_rn(__fadd_rn(rr[4], rr[5]), __fadd_rn(rr[6], rr[7])));
        float h1 = __fadd_rn(__fadd_rn(__fadd_rn(rr[8], rr[9]), __fadd_rn(rr[10], rr[11])),
                             __fadd_rn(__fadd_rn(rr[12], rr[13]), __fadd_rn(rr[14], rr[15])));
        dst[row] = __fadd_rn(h0, h1);
    }
}

// Same, but only for flagged rows (x2 is needed only in the exact fixup).
__global__ __launch_bounds__(64)
void np_sumsq_flagged_kernel(const float* __restrict__ ze,
                             const int* __restrict__ nflag,
                             const int* __restrict__ flags,
                             float* __restrict__ x2, int cap) {
    const int lane = threadIdx.x;
    const int nf   = min(nflag[0], cap);
    for (int f = blockIdx.x; f < nf; f += gridDim.x) {
        const int row = flags[f];
        const float* a = ze + (size_t)row * D;
        float r = 0.0f;
        if (lane < 16) {
            const float* h = a + (lane >> 3) * 128;
            const int j = lane & 7;
            float v = h[j];
            r = __fmul_rn(v, v);
            #pragma unroll
            for (int i = 8; i < 128; i += 8) {
                float u = h[i + j];
                r = __fadd_rn(r, __fmul_rn(u, u));
            }
        }
        float rr[16];
        #pragma unroll
        for (int t = 0; t < 16; ++t) rr[t] = __shfl(r, t, 64);
        if (lane == 0) {
            float h0 = __fadd_rn(__fadd_rn(__fadd_rn(rr[0], rr[1]), __fadd_rn(rr[2], rr[3])),
                                 __fadd_rn(__fadd_rn(rr[4], rr[5]), __fadd_rn(rr[6], rr[7])));
            float h1 = __fadd_rn(__fadd_rn(__fadd_rn(rr[8], rr[9]), __fadd_rn(rr[10], rr[11])),
                                 __fadd_rn(__fadd_rn(rr[12], rr[13]), __fadd_rn(rr[14], rr[15])));
            x2[row] = __fadd_rn(h0, h1);
        }
    }
}

// ---------------------------------------------------------------------------
// Pack codebook into 32x32x16 f16 MFMA A-fragment order (single split).
// ushort offset = ((t*16 + c)*64 + l)*8 + j
// value = fp16( cb[t*32 + (l&31)][c*16 + 8*(l>>5) + j] )
// (k-slot map k = 8*(l>>5)+j identical for A and B -> k-permutation cancels.)
// ---------------------------------------------------------------------------
__global__ __launch_bounds__(256)
void pack_cb_kernel(const float* __restrict__ cb, unsigned short* __restrict__ cbp) {
    const int t  = blockIdx.x;          // 256 tiles of 32 codes
    const int l  = threadIdx.x & 63;
    const int cq = threadIdx.x >> 6;
    const int row = t * 32 + (l & 31);
    const int db  = 8 * (l >> 5);
    #pragma unroll
    for (int ci = 0; ci < 4; ++ci) {
        const int c  = cq * 4 + ci;
        const int d0 = c * 16 + db;
        float4 v0 = *reinterpret_cast<const float4*>(&cb[(size_t)row * D + d0]);
        float4 v1 = *reinterpret_cast<const float4*>(&cb[(size_t)row * D + d0 + 4]);
        float xv[8] = {v0.x, v0.y, v0.z, v0.w, v1.x, v1.y, v1.z, v1.w};
        f16x8 hv;
        #pragma unroll
        for (int j = 0; j < 8; ++j) hv[j] = (_Float16)xv[j];
        *reinterpret_cast<f16x8*>(cbp + (((size_t)t * 16 + c) * 64 + l) * 8) = hv;
    }
}

// ---------------------------------------------------------------------------
// MFMA distance GEMM + per-row top-2, fp16 single-product, 32x32x16.
// 4 waves x 32 rows = 128 rows/block; K split 2 ways (blockIdx&1).
// B fragments 64 VGPR + 2 acc chains (32) + temps ~ 100 < 128 -> no spill.
// Skeleton (stage/dbuf/sched_barrier/barriers) identical to the round-9
// verified kernel; tile is 16KB (single split).
// score = c2[k] - 2*fl32(sum fp16(x)*fp16(c)); TAU_NEW covers the fp16 error.
// ---------------------------------------------------------------------------
__global__ __launch_bounds__(256)
void mfma_argmin_kernel(const float* __restrict__ ze,
                        const unsigned short* __restrict__ cbp,
                        const float* __restrict__ c2,
                        float2* __restrict__ tops, int* __restrict__ topi) {
    __shared__ unsigned short lds[2 * 8192];   // 2 x 16 KB tile buffers
    const int tid = threadIdx.x;
    const int l   = tid & 63;
    const int w   = tid >> 6;
    const int ks  = blockIdx.x & 1;
    const int nb  = blockIdx.x >> 1;
    const int n   = nb * 128 + w * 32 + (l & 31);
    const int h   = l >> 5;

    // ---- z rows -> fp16 B fragments, register-resident (64 VGPR)
    f16x8 Bf[16];
    {
        const float* zr = ze + (size_t)n * D + 8 * h;
        #pragma unroll
        for (int c = 0; c < 16; ++c) {
            float4 v0 = *reinterpret_cast<const float4*>(zr + c * 16);
            float4 v1 = *reinterpret_cast<const float4*>(zr + c * 16 + 4);
            float xv[8] = {v0.x, v0.y, v0.z, v0.w, v1.x, v1.y, v1.z, v1.w};
            f16x8 hv;
            #pragma unroll
            for (int j = 0; j < 8; ++j) hv[j] = (_Float16)xv[j];
            Bf[c] = hv;
        }
    }

    const int t0 = ks * 128;
    const uint4* gsrc = reinterpret_cast<const uint4*>(cbp);  // tile = 1024 uint4

    // async stage: wave w stages its quarter (256 uint4) via 4 calls
    auto stage = [&](int t, int buf) {
        const uint4* g = gsrc + (size_t)t * 1024 + w * 256 + l;
        uint4* lb = reinterpret_cast<uint4*>(lds + buf * 8192) + w * 256;
        #pragma unroll
        for (int r = 0; r < 4; ++r)
            gld16(g + r * 64, lb + r * 64);
    };

    stage(t0, 0);
    __builtin_amdgcn_sched_barrier(0);   // pin stage issue before the barrier
    __syncthreads();   // drains vmcnt: tile 0 resident

    float b1 = 3.4e38f, b2 = 3.4e38f;
    int   i1 = 0;
    int   cur = 0;

    for (int ti = 0; ti < 128; ++ti) {
        const int t = t0 + ti;
        if (ti + 1 < 128) stage(t + 1, cur ^ 1);    // async into other buffer
        __builtin_amdgcn_sched_barrier(0);           // stage must issue HERE

        const uint4* abuf = reinterpret_cast<const uint4*>(lds + cur * 8192);
        f32x16 a0, a1;    // even / odd chunk chains
        #pragma unroll
        for (int i = 0; i < 16; ++i) { a0[i] = 0.0f; a1[i] = 0.0f; }
        #pragma unroll
        for (int c = 0; c < 16; c += 2) {
            f16x8 A0 = __builtin_bit_cast(f16x8, abuf[(c + 0) * 64 + l]);
            f16x8 A1 = __builtin_bit_cast(f16x8, abuf[(c + 1) * 64 + l]);
            a0 = MFMAH(A0, Bf[c + 0], a0);
            a1 = MFMAH(A1, Bf[c + 1], a1);
        }
        // epilogue: scores + running top-2 (codes ascend in processing order)
        // D mapping (m74/m101): col=l&31 (z-row), row=(reg&3)+8*(reg>>2)+4*h
        const float* c2t = c2 + t * 32 + 4 * h;
        const int base = t * 32 + 4 * h;
        #pragma unroll
        for (int g = 0; g < 4; ++g) {
            float4 cv = *reinterpret_cast<const float4*>(c2t + 8 * g);
            #pragma unroll
            for (int q = 0; q < 4; ++q) {
                const int reg = g * 4 + q;
                float dot = a0[reg] + a1[reg];
                float cc  = (q == 0) ? cv.x : (q == 1) ? cv.y : (q == 2) ? cv.z : cv.w;
                float s   = fmaf(-2.0f, dot, cc);
                int code  = base + 8 * g + q;
                bool lt = s < b1;
                b2 = fminf(b2, lt ? b1 : s);
                i1 = lt ? code : i1;
                b1 = lt ? s : b1;
            }
        }
        __syncthreads();   // drains vmcnt (next tile staged) + frees buf[cur]
        cur ^= 1;
    }

    // merge lane l <-> l^32 (same row n)
    float ob1 = __shfl_xor(b1, 32);
    float ob2 = __shfl_xor(b2, 32);
    int   oi1 = __shfl_xor(i1, 32);
    bool take = (ob1 < b1) || (ob1 == b1 && oi1 < i1);
    float nb2 = fminf(fmaxf(b1, ob1), fminf(b2, ob2));
    float nb1 = take ? ob1 : b1;
    int   ni1 = take ? oi1 : i1;
    if (l < 32) {
        tops[(size_t)n * 2 + ks] = make_float2(nb1, nb2);
        topi[(size_t)n * 2 + ks] = ni1;
    }
}

// ---------------------------------------------------------------------------
// Merge the two k-split top-2 entries per row; flag near-ties (round-5).
// ---------------------------------------------------------------------------
__global__ __launch_bounds__(256)
void ksplit_merge_kernel(const float2* __restrict__ tops, const int* __restrict__ topi,
                         int* __restrict__ idx_out, float* __restrict__ idxf_out,
                         int* __restrict__ nflag, int* __restrict__ flags, float tau) {
    const int n = blockIdx.x * 256 + threadIdx.x;
    float2 e0 = tops[(size_t)n * 2 + 0];
    float2 e1 = tops[(size_t)n * 2 + 1];
    int    i0 = topi[(size_t)n * 2 + 0];
    int    i1v = topi[(size_t)n * 2 + 1];
    bool take = (e1.x < e0.x) || (e1.x == e0.x && i1v < i0);
    float b1 = take ? e1.x : e0.x;
    int   bi = take ? i1v : i0;
    float b2 = fminf(fmaxf(e0.x, e1.x), fminf(e0.y, e1.y));
    idx_out[n]  = bi;
    idxf_out[n] = (float)bi;
    if (b2 - b1 < tau) {
        int p = atomicAdd(nflag, 1);
        flags[p] = n;
    }
}

// ---------------------------------------------------------------------------
// Inverted-loop exact fixup, 16 row-stripes (round-5 body; grid 512 -> 8192:
// blockIdx = cb_block(512) + 512*stripe; loop f = stripe; f += nstripes).
// Writes scr[f*512 + cb_block] -- disjoint, deterministic.
// ---------------------------------------------------------------------------
__global__ __launch_bounds__(256)
void fix1_kernel(const float* __restrict__ ze, const float* __restrict__ cb,
                 const float* __restrict__ c2, const float* __restrict__ x2,
                 const int* __restrict__ nflag, const int* __restrict__ flags,
                 float* __restrict__ scr_s, int* __restrict__ scr_i, int cap) {
    __shared__ float sz[D];
    __shared__ float sbest[16];
    __shared__ int   sbi[16];
    const int tid     = threadIdx.x;
    const int cl      = tid >> 4;
    const int dt      = tid & 15;
    const int cbblk   = blockIdx.x & 511;
    const int stripe  = blockIdx.x >> 9;
    const int nstripe = gridDim.x >> 9;
    const int code    = cbblk * 16 + cl;
    const int nf      = min(nflag[0], cap);
    for (int f = stripe; f < nf; f += nstripe) {
        const int row = flags[f];
        __syncthreads();
        sz[tid] = ze[(size_t)row * D + tid];
        __syncthreads();
        double dot = 0.0;
        const float* cr = cb + (size_t)code * D + dt * 16;
        #pragma unroll
        for (int i = 0; i < 16; ++i)
            dot = fma((double)sz[dt * 16 + i], (double)cr[i], dot);
        #pragma unroll
        for (int o = 1; o < 16; o <<= 1)
            dot += __shfl_xor(dot, o);
        if (dt == 0) {
            float P  = (float)dot;
            float t3 = __fadd_rn(x2[row], __fmul_rn(-2.0f, P));
            float t4 = __fadd_rn(t3, c2[code]);
            sbest[cl] = t4; sbi[cl] = code;
        }
        __syncthreads();
        if (tid == 0) {
            float bs = sbest[0]; int bi = sbi[0];
            #pragma unroll
            for (int c = 1; c < 16; ++c)
                if (sbest[c] < bs) { bs = sbest[c]; bi = sbi[c]; }
            scr_s[(size_t)f * 512 + cbblk] = bs;
            scr_i[(size_t)f * 512 + cbblk] = bi;
        }
    }
}

__global__ __launch_bounds__(256)
void fix2_kernel(const int* __restrict__ nflag, const int* __restrict__ flags,
                 const float* __restrict__ scr_s, const int* __restrict__ scr_i,
                 int* __restrict__ idx_out, float* __restrict__ idxf_out, int cap) {
    __shared__ float ss[256];
    __shared__ int   si[256];
    const int tid = threadIdx.x;
    const int nf  = min(nflag[0], cap);
    for (int f = blockIdx.x; f < nf; f += gridDim.x) {
        float s0 = scr_s[(size_t)f * 512 + tid];
        int   j0 = scr_i[(size_t)f * 512 + tid];
        float s1 = scr_s[(size_t)f * 512 + 256 + tid];
        int   j1 = scr_i[(size_t)f * 512 + 256 + tid];
        bool take = (s1 < s0) || (s1 == s0 && j1 < j0);
        ss[tid] = take ? s1 : s0;
        si[tid] = take ? j1 : j0;
        __syncthreads();
        for (int o = 128; o; o >>= 1) {
            if (tid < o) {
                if (ss[tid + o] < ss[tid] ||
                    (ss[tid + o] == ss[tid] && si[tid + o] < si[tid])) {
                    ss[tid] = ss[tid + o]; si[tid] = si[tid + o];
                }
            }
            __syncthreads();
        }
        if (tid == 0) {
            const int row = flags[f];
            idx_out[row]  = si[0];
            idxf_out[row] = (float)si[0];
        }
        __syncthreads();
    }
}

// ---------------------------------------------------------------------------
// FALLBACK (round-3 verified): fp32 vector GEMM + top-2, fp64 fixup.
// ---------------------------------------------------------------------------
__global__ __launch_bounds__(512)
void argmin_fp32_kernel(const float* __restrict__ ze, const float* __restrict__ cb,
                        const float* __restrict__ c2,
                        int* __restrict__ idx_out, float* __restrict__ idxf_out,
                        int* __restrict__ nflag, int* __restrict__ flags) {
    __shared__ float smem[12672];
    float* a_s = smem;
    float* b_s = smem + 32 * 128;
    const int tid  = threadIdx.x;
    const int tx   = tid & 31;
    const int ty   = tid >> 5;
    const int row0 = blockIdx.x * 128;
    float b1[8], b2[8];
    int   i1[8];
    #pragma unroll
    for (int r = 0; r < 8; ++r) { b1[r] = 3.4e38f; b2[r] = 3.4e38f; i1[r] = 0; }
    for (int kt = 0; kt < K; kt += 256) {
        float acc[8][8];
        #pragma unroll
        for (int r = 0; r < 8; ++r)
            #pragma unroll
            for (int c = 0; c < 8; ++c) acc[r][c] = 0.0f;
        for (int dc = 0; dc < D; dc += 32) {
            __syncthreads();
            #pragma unroll
            for (int j = 0; j < 2; ++j) {
                int p = tid + j * 512, ar = p >> 3, ad = (p & 7) << 2;
                float4 v = *reinterpret_cast<const float4*>(&ze[(size_t)(row0 + ar) * D + dc + ad]);
                a_s[(ad + 0) * 128 + ar] = v.x; a_s[(ad + 1) * 128 + ar] = v.y;
                a_s[(ad + 2) * 128 + ar] = v.z; a_s[(ad + 3) * 128 + ar] = v.w;
            }
            #pragma unroll
            for (int j = 0; j < 4; ++j) {
                int p = tid + j * 512, br = p >> 3, bd = (p & 7) << 2;
                float4 v = *reinterpret_cast<const float4*>(&cb[(size_t)(kt + br) * D + dc + bd]);
                b_s[(bd + 0) * 256 + br] = v.x; b_s[(bd + 1) * 256 + br] = v.y;
                b_s[(bd + 2) * 256 + br] = v.z; b_s[(bd + 3) * 256 + br] = v.w;
            }
            __syncthreads();
            #pragma unroll 4
            for (int d = 0; d < 32; ++d) {
                float4 a0  = *reinterpret_cast<const float4*>(&a_s[d * 128 + ty * 4]);
                float4 a1  = *reinterpret_cast<const float4*>(&a_s[d * 128 + 64 + ty * 4]);
                float4 b0  = *reinterpret_cast<const float4*>(&b_s[d * 256 + tx * 4]);
                float4 b1v = *reinterpret_cast<const float4*>(&b_s[d * 256 + 128 + tx * 4]);
                float av[8] = {a0.x, a0.y, a0.z, a0.w, a1.x, a1.y, a1.z, a1.w};
                float bv[8] = {b0.x, b0.y, b0.z, b0.w, b1v.x, b1v.y, b1v.z, b1v.w};
                #pragma unroll
                for (int r = 0; r < 8; ++r)
                    #pragma unroll
                    for (int c = 0; c < 8; ++c)
                        acc[r][c] = fmaf(av[r], bv[c], acc[r][c]);
            }
        }
        float4 cs0 = *reinterpret_cast<const float4*>(&c2[kt + tx * 4]);
        float4 cs1 = *reinterpret_cast<const float4*>(&c2[kt + 128 + tx * 4]);
        float cv[8] = {cs0.x, cs0.y, cs0.z, cs0.w, cs1.x, cs1.y, cs1.z, cs1.w};
        #pragma unroll
        for (int r = 0; r < 8; ++r)
            #pragma unroll
            for (int c = 0; c < 8; ++c) {
                int col = kt + ((c < 4) ? (tx * 4 + c) : (128 + tx * 4 + (c - 4)));
                float s = fmaf(-2.0f, acc[r][c], cv[c]);
                if (s < b1[r]) { b2[r] = b1[r]; b1[r] = s; i1[r] = col; }
                else if (s < b2[r]) { b2[r] = s; }
            }
    }
    __syncthreads();
    float* rs1 = smem;
    int*   ri  = (int*)(smem + 4224);
    float* rs2 = smem + 8448;
    #pragma unroll
    for (int r = 0; r < 8; ++r) {
        int lrow = (r >> 2) * 64 + ty * 4 + (r & 3);
        rs1[lrow * 33 + tx] = b1[r]; ri[lrow * 33 + tx] = i1[r]; rs2[lrow * 33 + tx] = b2[r];
    }
    __syncthreads();
    if (tid < 128) {
        float B1 = 3.4e38f, B2 = 3.4e38f;
        int I1 = 0;
        #pragma unroll 4
        for (int t = 0; t < 32; ++t) {
            float s1 = rs1[tid * 33 + t]; int j1 = ri[tid * 33 + t]; float s2 = rs2[tid * 33 + t];
            if (s1 < B1 || (s1 == B1 && j1 < I1)) { B2 = fminf(B2, B1); B1 = s1; I1 = j1; }
            else B2 = fminf(B2, s1);
            B2 = fminf(B2, s2);
        }
        int grow = row0 + tid;
        idx_out[grow] = I1;
        idxf_out[grow] = (float)I1;
        if (B2 - B1 < TAU_OLD) { int p = atomicAdd(nflag, 1); flags[p] = grow; }
    }
}

__global__ __launch_bounds__(256)
void fix_old_kernel(const float* __restrict__ ze, const float* __restrict__ cb,
                    const float* __restrict__ c2, const float* __restrict__ x2,
                    const int* __restrict__ nflag, const int* __restrict__ flags,
                    int* __restrict__ idx_out, float* __restrict__ idxf_out) {
    __shared__ __align__(16) float sx[D];
    __shared__ float sbest[256];
    __shared__ int   sidx[256];
    const int tid = threadIdx.x;
    const int n   = nflag[0];
    for (int f = blockIdx.x; f < n; f += gridDim.x) {
        __syncthreads();
        const int row = flags[f];
        sx[tid] = ze[(size_t)row * D + tid];
        const float x2r = x2[row];
        __syncthreads();
        const float4* sx4 = reinterpret_cast<const float4*>(sx);
        float best = 3.4e38f; int bi = K;
        for (int k = tid; k < K; k += 256) {
            const float4* cbr = reinterpret_cast<const float4*>(&cb[(size_t)k * D]);
            double dot = 0.0;
            #pragma unroll 8
            for (int d4 = 0; d4 < D / 4; ++d4) {
                float4 c = cbr[d4]; float4 x = sx4[d4];
                dot = fma((double)x.x, (double)c.x, dot);
                dot = fma((double)x.y, (double)c.y, dot);
                dot = fma((double)x.z, (double)c.z, dot);
                dot = fma((double)x.w, (double)c.w, dot);
            }
            float P  = (float)dot;
            float t3 = __fadd_rn(x2r, __fmul_rn(-2.0f, P));
            float t4 = __fadd_rn(t3, c2[k]);
            if (t4 < best || (t4 == best && k < bi)) { best = t4; bi = k; }
        }
        sbest[tid] = best; sidx[tid] = bi;
        __syncthreads();
        for (int o = 128; o; o >>= 1) {
            if (tid < o) {
                if (sbest[tid + o] < sbest[tid] ||
                    (sbest[tid + o] == sbest[tid] && sidx[tid + o] < sidx[tid])) {
                    sbest[tid] = sbest[tid + o]; sidx[tid] = sidx[tid + o];
                }
            }
            __syncthreads();
        }
        if (tid == 0) { idx_out[row] = sidx[0]; idxf_out[row] = (float)sidx[0]; }
    }
}

// ---------------------------------------------------------------------------
// gather z_q = cb[idx] + loss reduction (deterministic two-stage)
// ---------------------------------------------------------------------------
__global__ __launch_bounds__(256)
void gather_loss_kernel(const float* __restrict__ ze, const float* __restrict__ cb,
                        const int* __restrict__ idx, float* __restrict__ zq,
                        float* __restrict__ partial) {
    const int tid  = threadIdx.x;
    const int w    = tid >> 6;
    const int lane = tid & 63;
    const int n    = blockIdx.x * 4 + w;
    const int k    = idx[n];
    float4 q = *reinterpret_cast<const float4*>(&cb[(size_t)k * D + lane * 4]);
    float4 z = *reinterpret_cast<const float4*>(&ze[(size_t)n * D + lane * 4]);
    *reinterpret_cast<float4*>(&zq[(size_t)n * D + lane * 4]) = q;
    float dx = z.x - q.x, dy = z.y - q.y, dz = z.z - q.z, dw = z.w - q.w;
    float s = dx * dx + dy * dy + dz * dz + dw * dw;
    #pragma unroll
    for (int o = 32; o; o >>= 1) s += __shfl_down(s, o);
    __shared__ float ws4[4];
    if (lane == 0) ws4[w] = s;
    __syncthreads();
    if (tid == 0) partial[blockIdx.x] = ws4[0] + ws4[1] + ws4[2] + ws4[3];
}

__global__ __launch_bounds__(256)
void final_loss_kernel(const float* __restrict__ partial, float* __restrict__ out) {
    __shared__ float sm[256];
    const int tid = threadIdx.x;
    float s = 0.0f;
    for (int i = tid; i < 8192; i += 256) s += partial[i];
    sm[tid] = s;
    __syncthreads();
    #pragma unroll
    for (int o = 128; o; o >>= 1) {
        if (tid < o) sm[tid] += sm[tid + o];
        __syncthreads();
    }
    if (tid == 0)
        out[0] = sm[0] * (1.0f + BETA) / (float)(NROWS * D);
}

// ---------------------------------------------------------------------------
extern "C" void kernel_launch(void* const* d_in, const int* in_sizes, int n_in,
                              void* d_out, int out_size, void* d_ws, size_t ws_size,
                              hipStream_t stream) {
    const float* ze = (const float*)d_in[0];
    const float* cb = (const float*)d_in[1];

    float* out  = (float*)d_out;
    float* zq   = out;
    float* idxf = out + (size_t)NROWS * D;
    float* loss = out + (size_t)NROWS * D + NROWS;

    char* ws = (char*)d_ws;
    float*  c2      = (float*) (ws);
    float*  x2      = (float*) (ws + 32768);
    int*    idx     = (int*)   (ws + 163840);
    float*  partial = (float*) (ws + 294912);
    int*    nflag   = (int*)   (ws + 327680);
    int*    flags   = (int*)   (ws + 327696);
    float2* tops    = (float2*)(ws + 458768);
    int*    topi    = (int*)   (ws + 983056);
    unsigned short* cbp = (unsigned short*)(ws + 1245200);   // 4.2 MB used (slot 8.4)
    float*  scr_s   = (float*) (ws + 9633808);
    const size_t scr_base = 9633808;

    const size_t need_min = scr_base + (size_t)2048 * 4096;
    const bool newpath = ws_size >= need_min;
    int cap = 0;
    int* scr_i = nullptr;
    if (newpath) {
        size_t avail = (ws_size - scr_base) / 4096;
        cap = (int)(avail > 8192 ? 8192 : avail);
        scr_i = (int*)(ws + scr_base + (size_t)cap * 2048);
    }

    hipMemsetAsync(nflag, 0, sizeof(int), stream);
    hipLaunchKernelGGL(np_sumsq_kernel, dim3(K / 4), dim3(256), 0, stream, cb, c2, K);

    if (newpath) {
        hipLaunchKernelGGL(pack_cb_kernel,     dim3(256), dim3(256), 0, stream, cb, cbp);
        hipLaunchKernelGGL(mfma_argmin_kernel, dim3(512), dim3(256), 0, stream,
                           ze, cbp, c2, tops, topi);
        hipLaunchKernelGGL(ksplit_merge_kernel, dim3(NROWS / 256), dim3(256), 0, stream,
                           tops, topi, idx, idxf, nflag, flags, TAU_NEW);
        hipLaunchKernelGGL(np_sumsq_flagged_kernel, dim3(256), dim3(64), 0, stream,
                           ze, nflag, flags, x2, cap);
        hipLaunchKernelGGL(fix1_kernel, dim3(8192), dim3(256), 0, stream,
                           ze, cb, c2, x2, nflag, flags, scr_s, scr_i, cap);
        hipLaunchKernelGGL(fix2_kernel, dim3(128), dim3(256), 0, stream,
                           nflag, flags, scr_s, scr_i, idx, idxf, cap);
    } else {
        hipLaunchKernelGGL(argmin_fp32_kernel, dim3(NROWS / 128), dim3(512), 0, stream,
                           ze, cb, c2, idx, idxf, nflag, flags);
        hipLaunchKernelGGL(np_sumsq_flagged_kernel, dim3(128), dim3(64), 0, stream,
                           ze, nflag, flags, x2, NROWS);
        hipLaunchKernelGGL(fix_old_kernel, dim3(256), dim3(256), 0, stream,
                           ze, cb, c2, x2, nflag, flags, idx, idxf);
    }

    hipLaunchKernelGGL(gather_loss_kernel, dim3(NROWS / 4), dim3(256), 0, stream,
                       ze, cb, idx, zq, partial);
    hipLaunchKernelGGL(final_loss_kernel, dim3(1), dim3(256), 0, stream,
                       partial, loss);
}

// Round 12
// 439.441 us; speedup vs baseline: 1.1884x; 1.1543x over previous
//
#include <hip/hip_runtime.h>

#define D     256
#define K     8192
#define NROWS 32768      // B*T
#define BETA  0.025f
#define TAU_NEW 2e-3f    // fp16 single-product margin (score err sigma ~2e-4)
#define TAU_OLD 2e-4f    // fp32 fallback path margin

typedef _Float16 f16x8 __attribute__((ext_vector_type(8)));
typedef unsigned short ushort8v __attribute__((ext_vector_type(8)));
typedef float f32x16 __attribute__((ext_vector_type(16)));

#define MFMAH(a,b,c) __builtin_amdgcn_mfma_f32_32x32x16_f16(a,b,c,0,0,0)

typedef __attribute__((address_space(3))) unsigned int lds_uint;
typedef __attribute__((address_space(1))) unsigned int glb_uint;
__device__ __forceinline__ void gld16(const void* g, void* l) {
    // async global->LDS, 16B/lane; LDS dest = wave-uniform base + lane*16
    __builtin_amdgcn_global_load_lds((const glb_uint*)g, (lds_uint*)l, 16, 0, 0);
}

// ---------------------------------------------------------------------------
// numpy-exact row sum-of-squares (pairwise_sum emulation, n=256); full rows
// ---------------------------------------------------------------------------
__global__ __launch_bounds__(256)
void np_sumsq_kernel(const float* __restrict__ src, float* __restrict__ dst,
                     int nrows) {
    const int tid  = threadIdx.x;
    const int w    = tid >> 6;
    const int lane = tid & 63;
    const int row  = blockIdx.x * 4 + w;
    if (row >= nrows) return;
    const float* a = src + (size_t)row * D;
    float r = 0.0f;
    if (lane < 16) {
        const float* h = a + (lane >> 3) * 128;
        const int j = lane & 7;
        float v = h[j];
        r = __fmul_rn(v, v);
        #pragma unroll
        for (int i = 8; i < 128; i += 8) {
            float u = h[i + j];
            r = __fadd_rn(r, __fmul_rn(u, u));
        }
    }
    float rr[16];
    #pragma unroll
    for (int t = 0; t < 16; ++t) rr[t] = __shfl(r, t, 64);
    if (lane == 0) {
        float h0 = __fadd_rn(__fadd_rn(__fadd_rn(rr[0], rr[1]), __fadd_rn(rr[2], rr[3])),
                             __fadd_rn(__fadd_rn(rr[4], rr[5]), __fadd_rn(rr[6], rr[7])));
        float h1 = __fadd_rn(__fadd_rn(__fadd_rn(rr[8], rr[9]), __fadd_rn(rr[10], rr[11])),
                             __fadd_rn(__fadd_rn(rr[12], rr[13]), __fadd_rn(rr[14], rr[15])));
        dst[row] = __fadd_rn(h0, h1);
    }
}

// Same, but only for flagged rows (x2 is needed only in the exact fixup).
__global__ __launch_bounds__(64)
void np_sumsq_flagged_kernel(const float* __restrict__ ze,
                             const int* __restrict__ nflag,
                             const int* __restrict__ flags,
                             float* __restrict__ x2, int cap) {
    const int lane = threadIdx.x;
    const int nf   = min(nflag[0], cap);
    for (int f = blockIdx.x; f < nf; f += gridDim.x) {
        const int row = flags[f];
        const float* a = ze + (size_t)row * D;
        float r = 0.0f;
        if (lane < 16) {
            const float* h = a + (lane >> 3) * 128;
            const int j = lane & 7;
            float v = h[j];
            r = __fmul_rn(v, v);
            #pragma unroll
            for (int i = 8; i < 128; i += 8) {
                float u = h[i + j];
                r = __fadd_rn(r, __fmul_rn(u, u));
            }
        }
        float rr[16];
        #pragma unroll
        for (int t = 0; t < 16; ++t) rr[t] = __shfl(r, t, 64);
        if (lane == 0) {
            float h0 = __fadd_rn(__fadd_rn(__fadd_rn(rr[0], rr[1]), __fadd_rn(rr[2], rr[3])),
                                 __fadd_rn(__fadd_rn(rr[4], rr[5]), __fadd_rn(rr[6], rr[7])));
            float h1 = __fadd_rn(__fadd_rn(__fadd_rn(rr[8], rr[9]), __fadd_rn(rr[10], rr[11])),
                                 __fadd_rn(__fadd_rn(rr[12], rr[13]), __fadd_rn(rr[14], rr[15])));
            x2[row] = __fadd_rn(h0, h1);
        }
    }
}

// ---------------------------------------------------------------------------
// Pack codebook into 32x32x16 f16 MFMA A-fragment order (single split).
// ushort offset = ((t*16 + c)*64 + l)*8 + j
// value = fp16( cb[t*32 + (l&31)][c*16 + 8*(l>>5) + j] )
// (k-slot map k = 8*(l>>5)+j identical for A and B -> k-permutation cancels.)
// ---------------------------------------------------------------------------
__global__ __launch_bounds__(256)
void pack_cb_kernel(const float* __restrict__ cb, unsigned short* __restrict__ cbp) {
    const int t  = blockIdx.x;          // 256 tiles of 32 codes
    const int l  = threadIdx.x & 63;
    const int cq = threadIdx.x >> 6;
    const int row = t * 32 + (l & 31);
    const int db  = 8 * (l >> 5);
    #pragma unroll
    for (int ci = 0; ci < 4; ++ci) {
        const int c  = cq * 4 + ci;
        const int d0 = c * 16 + db;
        float4 v0 = *reinterpret_cast<const float4*>(&cb[(size_t)row * D + d0]);
        float4 v1 = *reinterpret_cast<const float4*>(&cb[(size_t)row * D + d0 + 4]);
        float xv[8] = {v0.x, v0.y, v0.z, v0.w, v1.x, v1.y, v1.z, v1.w};
        f16x8 hv;
        #pragma unroll
        for (int j = 0; j < 8; ++j) hv[j] = (_Float16)xv[j];
        *reinterpret_cast<f16x8*>(cbp + (((size_t)t * 16 + c) * 64 + l) * 8) = hv;
    }
}

// ---------------------------------------------------------------------------
// MFMA distance GEMM + per-row top-2, fp16 single-product, 32x32x16.
// (round-11 verified, unchanged)
// ---------------------------------------------------------------------------
__global__ __launch_bounds__(256)
void mfma_argmin_kernel(const float* __restrict__ ze,
                        const unsigned short* __restrict__ cbp,
                        const float* __restrict__ c2,
                        float2* __restrict__ tops, int* __restrict__ topi) {
    __shared__ unsigned short lds[2 * 8192];   // 2 x 16 KB tile buffers
    const int tid = threadIdx.x;
    const int l   = tid & 63;
    const int w   = tid >> 6;
    const int ks  = blockIdx.x & 1;
    const int nb  = blockIdx.x >> 1;
    const int n   = nb * 128 + w * 32 + (l & 31);
    const int h   = l >> 5;

    // ---- z rows -> fp16 B fragments, register-resident (64 VGPR)
    f16x8 Bf[16];
    {
        const float* zr = ze + (size_t)n * D + 8 * h;
        #pragma unroll
        for (int c = 0; c < 16; ++c) {
            float4 v0 = *reinterpret_cast<const float4*>(zr + c * 16);
            float4 v1 = *reinterpret_cast<const float4*>(zr + c * 16 + 4);
            float xv[8] = {v0.x, v0.y, v0.z, v0.w, v1.x, v1.y, v1.z, v1.w};
            f16x8 hv;
            #pragma unroll
            for (int j = 0; j < 8; ++j) hv[j] = (_Float16)xv[j];
            Bf[c] = hv;
        }
    }

    const int t0 = ks * 128;
    const uint4* gsrc = reinterpret_cast<const uint4*>(cbp);  // tile = 1024 uint4

    // async stage: wave w stages its quarter (256 uint4) via 4 calls
    auto stage = [&](int t, int buf) {
        const uint4* g = gsrc + (size_t)t * 1024 + w * 256 + l;
        uint4* lb = reinterpret_cast<uint4*>(lds + buf * 8192) + w * 256;
        #pragma unroll
        for (int r = 0; r < 4; ++r)
            gld16(g + r * 64, lb + r * 64);
    };

    stage(t0, 0);
    __builtin_amdgcn_sched_barrier(0);   // pin stage issue before the barrier
    __syncthreads();   // drains vmcnt: tile 0 resident

    float b1 = 3.4e38f, b2 = 3.4e38f;
    int   i1 = 0;
    int   cur = 0;

    for (int ti = 0; ti < 128; ++ti) {
        const int t = t0 + ti;
        if (ti + 1 < 128) stage(t + 1, cur ^ 1);    // async into other buffer
        __builtin_amdgcn_sched_barrier(0);           // stage must issue HERE

        const uint4* abuf = reinterpret_cast<const uint4*>(lds + cur * 8192);
        f32x16 a0, a1;    // even / odd chunk chains
        #pragma unroll
        for (int i = 0; i < 16; ++i) { a0[i] = 0.0f; a1[i] = 0.0f; }
        #pragma unroll
        for (int c = 0; c < 16; c += 2) {
            f16x8 A0 = __builtin_bit_cast(f16x8, abuf[(c + 0) * 64 + l]);
            f16x8 A1 = __builtin_bit_cast(f16x8, abuf[(c + 1) * 64 + l]);
            a0 = MFMAH(A0, Bf[c + 0], a0);
            a1 = MFMAH(A1, Bf[c + 1], a1);
        }
        // epilogue: scores + running top-2 (codes ascend in processing order)
        // D mapping (m74/m101): col=l&31 (z-row), row=(reg&3)+8*(reg>>2)+4*h
        const float* c2t = c2 + t * 32 + 4 * h;
        const int base = t * 32 + 4 * h;
        #pragma unroll
        for (int g = 0; g < 4; ++g) {
            float4 cv = *reinterpret_cast<const float4*>(c2t + 8 * g);
            #pragma unroll
            for (int q = 0; q < 4; ++q) {
                const int reg = g * 4 + q;
                float dot = a0[reg] + a1[reg];
                float cc  = (q == 0) ? cv.x : (q == 1) ? cv.y : (q == 2) ? cv.z : cv.w;
                float s   = fmaf(-2.0f, dot, cc);
                int code  = base + 8 * g + q;
                bool lt = s < b1;
                b2 = fminf(b2, lt ? b1 : s);
                i1 = lt ? code : i1;
                b1 = lt ? s : b1;
            }
        }
        __syncthreads();   // drains vmcnt (next tile staged) + frees buf[cur]
        cur ^= 1;
    }

    // merge lane l <-> l^32 (same row n)
    float ob1 = __shfl_xor(b1, 32);
    float ob2 = __shfl_xor(b2, 32);
    int   oi1 = __shfl_xor(i1, 32);
    bool take = (ob1 < b1) || (ob1 == b1 && oi1 < i1);
    float nb2 = fminf(fmaxf(b1, ob1), fminf(b2, ob2));
    float nb1 = take ? ob1 : b1;
    int   ni1 = take ? oi1 : i1;
    if (l < 32) {
        tops[(size_t)n * 2 + ks] = make_float2(nb1, nb2);
        topi[(size_t)n * 2 + ks] = ni1;
    }
}

// ---------------------------------------------------------------------------
// Merge the two k-split top-2 entries per row; flag near-ties (round-5).
// ---------------------------------------------------------------------------
__global__ __launch_bounds__(256)
void ksplit_merge_kernel(const float2* __restrict__ tops, const int* __restrict__ topi,
                         int* __restrict__ idx_out, float* __restrict__ idxf_out,
                         int* __restrict__ nflag, int* __restrict__ flags, float tau) {
    const int n = blockIdx.x * 256 + threadIdx.x;
    float2 e0 = tops[(size_t)n * 2 + 0];
    float2 e1 = tops[(size_t)n * 2 + 1];
    int    i0 = topi[(size_t)n * 2 + 0];
    int    i1v = topi[(size_t)n * 2 + 1];
    bool take = (e1.x < e0.x) || (e1.x == e0.x && i1v < i0);
    float b1 = take ? e1.x : e0.x;
    int   bi = take ? i1v : i0;
    float b2 = fminf(fmaxf(e0.x, e1.x), fminf(e0.y, e1.y));
    idx_out[n]  = bi;
    idxf_out[n] = (float)bi;
    if (b2 - b1 < tau) {
        int p = atomicAdd(nflag, 1);
        flags[p] = n;
    }
}

// ---------------------------------------------------------------------------
// Inverted-loop exact fixup, 16 row-stripes. ROUND-12 CHANGES (body only;
// grid/write-pattern identical to the round-11 passing build):
//  - cb slice hoisted to fp64 REGISTERS once per block (was: reloaded from
//    cache every flagged row).
//  - element partition i = dt + 16j (was dt*16+i): sz reads are 16
//    consecutive banks + cross-group broadcast -> conflict-free (round-11
//    counters: 5.4e7 bank-conflict cycles from the stride-16 pattern).
//  - fp64 dot order changes only in associativity (~1e-16; P=fl32(dot)
//    unaffected except astronomically rare boundary straddles).
// ---------------------------------------------------------------------------
__global__ __launch_bounds__(256)
void fix1_kernel(const float* __restrict__ ze, const float* __restrict__ cb,
                 const float* __restrict__ c2, const float* __restrict__ x2,
                 const int* __restrict__ nflag, const int* __restrict__ flags,
                 float* __restrict__ scr_s, int* __restrict__ scr_i, int cap) {
    __shared__ float sz[D];
    __shared__ float sbest[16];
    __shared__ int   sbi[16];
    const int tid     = threadIdx.x;
    const int cl      = tid >> 4;
    const int dt      = tid & 15;
    const int cbblk   = blockIdx.x & 511;
    const int stripe  = blockIdx.x >> 9;
    const int nstripe = gridDim.x >> 9;
    const int code    = cbblk * 16 + cl;
    const int nf      = min(nflag[0], cap);
    if (nf == 0) return;
    // hoist this block's cb slice into fp64 registers (once per block)
    double cbr[16];
    {
        const float* crp = cb + (size_t)code * D + dt;
        #pragma unroll
        for (int j = 0; j < 16; ++j) cbr[j] = (double)crp[16 * j];
    }
    const float cc = c2[code];
    for (int f = stripe; f < nf; f += nstripe) {
        const int row = flags[f];
        __syncthreads();
        sz[tid] = ze[(size_t)row * D + tid];
        __syncthreads();
        double dot = 0.0;
        #pragma unroll
        for (int j = 0; j < 16; ++j)
            dot = fma((double)sz[dt + 16 * j], cbr[j], dot);
        #pragma unroll
        for (int o = 1; o < 16; o <<= 1)
            dot += __shfl_xor(dot, o);
        if (dt == 0) {
            float P  = (float)dot;
            float t3 = __fadd_rn(x2[row], __fmul_rn(-2.0f, P));
            float t4 = __fadd_rn(t3, cc);
            sbest[cl] = t4; sbi[cl] = code;
        }
        __syncthreads();
        if (tid == 0) {
            float bs = sbest[0]; int bi = sbi[0];
            #pragma unroll
            for (int c = 1; c < 16; ++c)
                if (sbest[c] < bs) { bs = sbest[c]; bi = sbi[c]; }
            scr_s[(size_t)f * 512 + cbblk] = bs;
            scr_i[(size_t)f * 512 + cbblk] = bi;
        }
    }
}

__global__ __launch_bounds__(256)
void fix2_kernel(const int* __restrict__ nflag, const int* __restrict__ flags,
                 const float* __restrict__ scr_s, const int* __restrict__ scr_i,
                 int* __restrict__ idx_out, float* __restrict__ idxf_out, int cap) {
    __shared__ float ss[256];
    __shared__ int   si[256];
    const int tid = threadIdx.x;
    const int nf  = min(nflag[0], cap);
    for (int f = blockIdx.x; f < nf; f += gridDim.x) {
        float s0 = scr_s[(size_t)f * 512 + tid];
        int   j0 = scr_i[(size_t)f * 512 + tid];
        float s1 = scr_s[(size_t)f * 512 + 256 + tid];
        int   j1 = scr_i[(size_t)f * 512 + 256 + tid];
        bool take = (s1 < s0) || (s1 == s0 && j1 < j0);
        ss[tid] = take ? s1 : s0;
        si[tid] = take ? j1 : j0;
        __syncthreads();
        for (int o = 128; o; o >>= 1) {
            if (tid < o) {
                if (ss[tid + o] < ss[tid] ||
                    (ss[tid + o] == ss[tid] && si[tid + o] < si[tid])) {
                    ss[tid] = ss[tid + o]; si[tid] = si[tid + o];
                }
            }
            __syncthreads();
        }
        if (tid == 0) {
            const int row = flags[f];
            idx_out[row]  = si[0];
            idxf_out[row] = (float)si[0];
        }
        __syncthreads();
    }
}

// ---------------------------------------------------------------------------
// FALLBACK (round-3 verified): fp32 vector GEMM + top-2, fp64 fixup.
// ---------------------------------------------------------------------------
__global__ __launch_bounds__(512)
void argmin_fp32_kernel(const float* __restrict__ ze, const float* __restrict__ cb,
                        const float* __restrict__ c2,
                        int* __restrict__ idx_out, float* __restrict__ idxf_out,
                        int* __restrict__ nflag, int* __restrict__ flags) {
    __shared__ float smem[12672];
    float* a_s = smem;
    float* b_s = smem + 32 * 128;
    const int tid  = threadIdx.x;
    const int tx   = tid & 31;
    const int ty   = tid >> 5;
    const int row0 = blockIdx.x * 128;
    float b1[8], b2[8];
    int   i1[8];
    #pragma unroll
    for (int r = 0; r < 8; ++r) { b1[r] = 3.4e38f; b2[r] = 3.4e38f; i1[r] = 0; }
    for (int kt = 0; kt < K; kt += 256) {
        float acc[8][8];
        #pragma unroll
        for (int r = 0; r < 8; ++r)
            #pragma unroll
            for (int c = 0; c < 8; ++c) acc[r][c] = 0.0f;
        for (int dc = 0; dc < D; dc += 32) {
            __syncthreads();
            #pragma unroll
            for (int j = 0; j < 2; ++j) {
                int p = tid + j * 512, ar = p >> 3, ad = (p & 7) << 2;
                float4 v = *reinterpret_cast<const float4*>(&ze[(size_t)(row0 + ar) * D + dc + ad]);
                a_s[(ad + 0) * 128 + ar] = v.x; a_s[(ad + 1) * 128 + ar] = v.y;
                a_s[(ad + 2) * 128 + ar] = v.z; a_s[(ad + 3) * 128 + ar] = v.w;
            }
            #pragma unroll
            for (int j = 0; j < 4; ++j) {
                int p = tid + j * 512, br = p >> 3, bd = (p & 7) << 2;
                float4 v = *reinterpret_cast<const float4*>(&cb[(size_t)(kt + br) * D + dc + bd]);
                b_s[(bd + 0) * 256 + br] = v.x; b_s[(bd + 1) * 256 + br] = v.y;
                b_s[(bd + 2) * 256 + br] = v.z; b_s[(bd + 3) * 256 + br] = v.w;
            }
            __syncthreads();
            #pragma unroll 4
            for (int d = 0; d < 32; ++d) {
                float4 a0  = *reinterpret_cast<const float4*>(&a_s[d * 128 + ty * 4]);
                float4 a1  = *reinterpret_cast<const float4*>(&a_s[d * 128 + 64 + ty * 4]);
                float4 b0  = *reinterpret_cast<const float4*>(&b_s[d * 256 + tx * 4]);
                float4 b1v = *reinterpret_cast<const float4*>(&b_s[d * 256 + 128 + tx * 4]);
                float av[8] = {a0.x, a0.y, a0.z, a0.w, a1.x, a1.y, a1.z, a1.w};
                float bv[8] = {b0.x, b0.y, b0.z, b0.w, b1v.x, b1v.y, b1v.z, b1v.w};
                #pragma unroll
                for (int r = 0; r < 8; ++r)
                    #pragma unroll
                    for (int c = 0; c < 8; ++c)
                        acc[r][c] = fmaf(av[r], bv[c], acc[r][c]);
            }
        }
        float4 cs0 = *reinterpret_cast<const float4*>(&c2[kt + tx * 4]);
        float4 cs1 = *reinterpret_cast<const float4*>(&c2[kt + 128 + tx * 4]);
        float cv[8] = {cs0.x, cs0.y, cs0.z, cs0.w, cs1.x, cs1.y, cs1.z, cs1.w};
        #pragma unroll
        for (int r = 0; r < 8; ++r)
            #pragma unroll
            for (int c = 0; c < 8; ++c) {
                int col = kt + ((c < 4) ? (tx * 4 + c) : (128 + tx * 4 + (c - 4)));
                float s = fmaf(-2.0f, acc[r][c], cv[c]);
                if (s < b1[r]) { b2[r] = b1[r]; b1[r] = s; i1[r] = col; }
                else if (s < b2[r]) { b2[r] = s; }
            }
    }
    __syncthreads();
    float* rs1 = smem;
    int*   ri  = (int*)(smem + 4224);
    float* rs2 = smem + 8448;
    #pragma unroll
    for (int r = 0; r < 8; ++r) {
        int lrow = (r >> 2) * 64 + ty * 4 + (r & 3);
        rs1[lrow * 33 + tx] = b1[r]; ri[lrow * 33 + tx] = i1[r]; rs2[lrow * 33 + tx] = b2[r];
    }
    __syncthreads();
    if (tid < 128) {
        float B1 = 3.4e38f, B2 = 3.4e38f;
        int I1 = 0;
        #pragma unroll 4
        for (int t = 0; t < 32; ++t) {
            float s1 = rs1[tid * 33 + t]; int j1 = ri[tid * 33 + t]; float s2 = rs2[tid * 33 + t];
            if (s1 < B1 || (s1 == B1 && j1 < I1)) { B2 = fminf(B2, B1); B1 = s1; I1 = j1; }
            else B2 = fminf(B2, s1);
            B2 = fminf(B2, s2);
        }
        int grow = row0 + tid;
        idx_out[grow] = I1;
        idxf_out[grow] = (float)I1;
        if (B2 - B1 < TAU_OLD) { int p = atomicAdd(nflag, 1); flags[p] = grow; }
    }
}

__global__ __launch_bounds__(256)
void fix_old_kernel(const float* __restrict__ ze, const float* __restrict__ cb,
                    const float* __restrict__ c2, const float* __restrict__ x2,
                    const int* __restrict__ nflag, const int* __restrict__ flags,
                    int* __restrict__ idx_out, float* __restrict__ idxf_out) {
    __shared__ __align__(16) float sx[D];
    __shared__ float sbest[256];
    __shared__ int   sidx[256];
    const int tid = threadIdx.x;
    const int n   = nflag[0];
    for (int f = blockIdx.x; f < n; f += gridDim.x) {
        __syncthreads();
        const int row = flags[f];
        sx[tid] = ze[(size_t)row * D + tid];
        const float x2r = x2[row];
        __syncthreads();
        const float4* sx4 = reinterpret_cast<const float4*>(sx);
        float best = 3.4e38f; int bi = K;
        for (int k = tid; k < K; k += 256) {
            const float4* cbr = reinterpret_cast<const float4*>(&cb[(size_t)k * D]);
            double dot = 0.0;
            #pragma unroll 8
            for (int d4 = 0; d4 < D / 4; ++d4) {
                float4 c = cbr[d4]; float4 x = sx4[d4];
                dot = fma((double)x.x, (double)c.x, dot);
                dot = fma((double)x.y, (double)c.y, dot);
                dot = fma((double)x.z, (double)c.z, dot);
                dot = fma((double)x.w, (double)c.w, dot);
            }
            float P  = (float)dot;
            float t3 = __fadd_rn(x2r, __fmul_rn(-2.0f, P));
            float t4 = __fadd_rn(t3, c2[k]);
            if (t4 < best || (t4 == best && k < bi)) { best = t4; bi = k; }
        }
        sbest[tid] = best; sidx[tid] = bi;
        __syncthreads();
        for (int o = 128; o; o >>= 1) {
            if (tid < o) {
                if (sbest[tid + o] < sbest[tid] ||
                    (sbest[tid + o] == sbest[tid] && sidx[tid + o] < sidx[tid])) {
                    sbest[tid] = sbest[tid + o]; sidx[tid] = sidx[tid + o];
                }
            }
            __syncthreads();
        }
        if (tid == 0) { idx_out[row] = sidx[0]; idxf_out[row] = (float)sidx[0]; }
    }
}

// ---------------------------------------------------------------------------
// gather z_q = cb[idx] + loss reduction (deterministic two-stage)
// ---------------------------------------------------------------------------
__global__ __launch_bounds__(256)
void gather_loss_kernel(const float* __restrict__ ze, const float* __restrict__ cb,
                        const int* __restrict__ idx, float* __restrict__ zq,
                        float* __restrict__ partial) {
    const int tid  = threadIdx.x;
    const int w    = tid >> 6;
    const int lane = tid & 63;
    const int n    = blockIdx.x * 4 + w;
    const int k    = idx[n];
    float4 q = *reinterpret_cast<const float4*>(&cb[(size_t)k * D + lane * 4]);
    float4 z = *reinterpret_cast<const float4*>(&ze[(size_t)n * D + lane * 4]);
    *reinterpret_cast<float4*>(&zq[(size_t)n * D + lane * 4]) = q;
    float dx = z.x - q.x, dy = z.y - q.y, dz = z.z - q.z, dw = z.w - q.w;
    float s = dx * dx + dy * dy + dz * dz + dw * dw;
    #pragma unroll
    for (int o = 32; o; o >>= 1) s += __shfl_down(s, o);
    __shared__ float ws4[4];
    if (lane == 0) ws4[w] = s;
    __syncthreads();
    if (tid == 0) partial[blockIdx.x] = ws4[0] + ws4[1] + ws4[2] + ws4[3];
}

__global__ __launch_bounds__(256)
void final_loss_kernel(const float* __restrict__ partial, float* __restrict__ out) {
    __shared__ float sm[256];
    const int tid = threadIdx.x;
    float s = 0.0f;
    for (int i = tid; i < 8192; i += 256) s += partial[i];
    sm[tid] = s;
    __syncthreads();
    #pragma unroll
    for (int o = 128; o; o >>= 1) {
        if (tid < o) sm[tid] += sm[tid + o];
        __syncthreads();
    }
    if (tid == 0)
        out[0] = sm[0] * (1.0f + BETA) / (float)(NROWS * D);
}

// ---------------------------------------------------------------------------
extern "C" void kernel_launch(void* const* d_in, const int* in_sizes, int n_in,
                              void* d_out, int out_size, void* d_ws, size_t ws_size,
                              hipStream_t stream) {
    const float* ze = (const float*)d_in[0];
    const float* cb = (const float*)d_in[1];

    float* out  = (float*)d_out;
    float* zq   = out;
    float* idxf = out + (size_t)NROWS * D;
    float* loss = out + (size_t)NROWS * D + NROWS;

    char* ws = (char*)d_ws;
    float*  c2      = (float*) (ws);
    float*  x2      = (float*) (ws + 32768);
    int*    idx     = (int*)   (ws + 163840);
    float*  partial = (float*) (ws + 294912);
    int*    nflag   = (int*)   (ws + 327680);
    int*    flags   = (int*)   (ws + 327696);
    float2* tops    = (float2*)(ws + 458768);
    int*    topi    = (int*)   (ws + 983056);
    unsigned short* cbp = (unsigned short*)(ws + 1245200);   // 4.2 MB used (slot 8.4)
    float*  scr_s   = (float*) (ws + 9633808);
    const size_t scr_base = 9633808;

    const size_t need_min = scr_base + (size_t)2048 * 4096;
    const bool newpath = ws_size >= need_min;
    int cap = 0;
    int* scr_i = nullptr;
    if (newpath) {
        size_t avail = (ws_size - scr_base) / 4096;
        cap = (int)(avail > 8192 ? 8192 : avail);
        scr_i = (int*)(ws + scr_base + (size_t)cap * 2048);
    }

    hipMemsetAsync(nflag, 0, sizeof(int), stream);
    hipLaunchKernelGGL(np_sumsq_kernel, dim3(K / 4), dim3(256), 0, stream, cb, c2, K);

    if (newpath) {
        hipLaunchKernelGGL(pack_cb_kernel,     dim3(256), dim3(256), 0, stream, cb, cbp);
        hipLaunchKernelGGL(mfma_argmin_kernel, dim3(512), dim3(256), 0, stream,
                           ze, cbp, c2, tops, topi);
        hipLaunchKernelGGL(ksplit_merge_kernel, dim3(NROWS / 256), dim3(256), 0, stream,
                           tops, topi, idx, idxf, nflag, flags, TAU_NEW);
        hipLaunchKernelGGL(np_sumsq_flagged_kernel, dim3(256), dim3(64), 0, stream,
                           ze, nflag, flags, x2, cap);
        hipLaunchKernelGGL(fix1_kernel, dim3(8192), dim3(256), 0, stream,
                           ze, cb, c2, x2, nflag, flags, scr_s, scr_i, cap);
        hipLaunchKernelGGL(fix2_kernel, dim3(128), dim3(256), 0, stream,
                           nflag, flags, scr_s, scr_i, idx, idxf, cap);
    } else {
        hipLaunchKernelGGL(argmin_fp32_kernel, dim3(NROWS / 128), dim3(512), 0, stream,
                           ze, cb, c2, idx, idxf, nflag, flags);
        hipLaunchKernelGGL(np_sumsq_flagged_kernel, dim3(128), dim3(64), 0, stream,
                           ze, nflag, flags, x2, NROWS);
        hipLaunchKernelGGL(fix_old_kernel, dim3(256), dim3(256), 0, stream,
                           ze, cb, c2, x2, nflag, flags, idx, idxf);
    }

    hipLaunchKernelGGL(gather_loss_kernel, dim3(NROWS / 4), dim3(256), 0, stream,
                       ze, cb, idx, zq, partial);
    hipLaunchKernelGGL(final_loss_kernel, dim3(1), dim3(256), 0, stream,
                       partial, loss);
}